// Round 6
// baseline (314.151 us; speedup 1.0000x reference)
//
#include <hip/hip_runtime.h>
#include <math.h>

#define NODES 100000
#define NEDGE 1600000
#define ETOT  (NEDGE + NODES)
#define FIN   128
#define C1    64
#define NEG   0.2f
#define BNEPS 1e-5f
#define BNBLK 256

#define BK     512                         // nodes per bucket
#define NBUCK  ((NODES + BK - 1) / BK)     // 196
#define PCAP   12288                       // per-bucket edge capacity (mean 8673, +38 sigma)
#define PTILE  4096                        // edges per k_part block

// ---------------- bucketed CSR build ----------------

__global__ __launch_bounds__(256) void k_zero256(int* p) {
    p[threadIdx.x] = 0;
}

// P1: partition edges into buckets by dst>>9; pack src | (dst&511)<<17
__global__ __launch_bounds__(256) void k_part(const int* __restrict__ ei, int* bcur,
                                              unsigned* __restrict__ tmp) {
    __shared__ int hist[256], hbase[256], run[256];
    int t = threadIdx.x;
    hist[t] = 0; run[t] = 0;
    __syncthreads();
    const int* srcs = ei;
    const int* dsts = ei + NEDGE;
    int e_base = blockIdx.x * PTILE;
    unsigned pack[16];
    int bkt[16];
    #pragma unroll
    for (int i = 0; i < 16; i++) {
        int e = e_base + i * 256 + t;
        bool valid = e < NEDGE;
        int s = valid ? srcs[e] : 0;
        int d = valid ? dsts[e] : 0;
        if ((unsigned)d >= NODES || (unsigned)s >= NODES) valid = false;
        bkt[i] = valid ? (d >> 9) : -1;
        pack[i] = (unsigned)s | ((unsigned)(d & (BK - 1)) << 17);
        if (valid) atomicAdd(&hist[bkt[i]], 1);
    }
    __syncthreads();
    hbase[t] = hist[t] ? atomicAdd(&bcur[t], hist[t]) : 0;
    __syncthreads();
    #pragma unroll
    for (int i = 0; i < 16; i++) {
        if (bkt[i] >= 0) {
            int slot = atomicAdd(&run[bkt[i]], 1) + hbase[bkt[i]];
            if (slot < PCAP) tmp[(size_t)bkt[i] * PCAP + slot] = pack[i];
        }
    }
}

// exclusive scan of 256 bucket totals
__global__ __launch_bounds__(256) void k_bscan(const int* __restrict__ bcur, int* __restrict__ bbase) {
    __shared__ int lds[256];
    int t = threadIdx.x;
    int own = bcur[t];
    lds[t] = own;
    __syncthreads();
    for (int o = 1; o < 256; o <<= 1) {
        int add = (t >= o) ? lds[t - o] : 0;
        __syncthreads();
        lds[t] += add;
        __syncthreads();
    }
    bbase[t] = lds[t] - own;
}

// P2: per bucket: per-node counts -> local scan (offs) -> LDS scatter -> coalesced csr write
__global__ __launch_bounds__(256) void k_build(const unsigned* __restrict__ tmp, const int* __restrict__ bcur,
                                               const int* __restrict__ bbase, int* __restrict__ offs,
                                               int* __restrict__ csr) {
    __shared__ int cnt[BK];        // per-node edge count, then cursor
    __shared__ int ps[256];        // pair-sum scan
    __shared__ int stage[PCAP + BK];
    int t = threadIdx.x;
    int b = blockIdx.x;
    int ecnt = bcur[b]; if (ecnt > PCAP) ecnt = PCAP;
    int csrbase = bbase[b] + BK * b;   // all earlier buckets have BK valid nodes (self-loops)
    const unsigned* ebuf = tmp + (size_t)b * PCAP;

    cnt[t] = 0; cnt[t + 256] = 0;
    __syncthreads();
    for (int e = t; e < ecnt; e += 256) {
        int dl = (ebuf[e] >> 17) & (BK - 1);
        atomicAdd(&cnt[dl], 1);
    }
    __syncthreads();
    // local exclusive scan over 512 counts (+1 self-loop per valid node)
    int i0 = 2 * t, i1 = 2 * t + 1;
    int g0 = b * BK + i0, g1 = b * BK + i1;
    int c0 = cnt[i0] + (g0 < NODES ? 1 : 0);
    int c1 = cnt[i1] + (g1 < NODES ? 1 : 0);
    int own = c0 + c1;
    ps[t] = own;
    __syncthreads();
    for (int o = 1; o < 256; o <<= 1) {
        int add = (t >= o) ? ps[t - o] : 0;
        __syncthreads();
        ps[t] += add;
        __syncthreads();
    }
    int excl0 = ps[t] - own;
    int excl1 = excl0 + c0;
    int total = ps[255];
    __syncthreads();
    // cursors + self-loops + offs
    if (g0 < NODES) {
        stage[excl0] = g0;
        cnt[i0] = excl0 + 1;
        offs[g0] = csrbase + excl0;
    }
    if (g1 < NODES) {
        stage[excl1] = g1;
        cnt[i1] = excl1 + 1;
        offs[g1] = csrbase + excl1;
    }
    if (b == NBUCK - 1 && t == 0) offs[NODES] = ETOT;
    __syncthreads();
    for (int e = t; e < ecnt; e += 256) {
        unsigned p = ebuf[e];
        int dl = (p >> 17) & (BK - 1);
        int slot = atomicAdd(&cnt[dl], 1);
        stage[slot] = (int)(p & 0x1FFFFu);
    }
    __syncthreads();
    for (int j = t; j < total; j += 256) csr[csrbase + j] = stage[j];
}

// ---------------- small precomputed vectors ----------------

__global__ __launch_bounds__(128) void k_prep(const float* __restrict__ W1d, const float* __restrict__ a1d,
                                              const float* __restrict__ W2d, const float* __restrict__ a2d,
                                              float* wad1, float* wad2) {
    int t = threadIdx.x;
    if (t < FIN) {
        float acc = 0.f;
        for (int c = 0; c < C1; c++) acc = fmaf(W1d[t * C1 + c], a1d[c], acc);
        wad1[t] = acc;
    }
    if (t < C1) {
        wad2[t] = fmaf(W2d[t * 2], a2d[0], W2d[t * 2 + 1] * a2d[1]);
    }
}

// ---------------- GEMM1: hs1 = x@W1_src, ad1 = x@wad1, as1 = hs1@a1_src ----------------
// 256 threads = 64 node-quads x 4 channel-groups. Thread: 4 consecutive nodes x 16 ch.
// W (+wad) in LDS, read wave-uniform (4 b128 per k, amortized over 4 nodes = 16 FMA/read).
// x read from global into registers (L1 line reuse within thread). acc = 64 VGPRs.

__global__ __launch_bounds__(256) void k_gemm1(const float* __restrict__ x, const float* __restrict__ Ws,
                                               const float* __restrict__ wad, const float* __restrict__ a_src,
                                               float* __restrict__ hs, float* __restrict__ as_out,
                                               float* __restrict__ ad_out) {
    __shared__ float Wt[FIN][C1 + 4];    // 34.8 KB; row = 64 ch (+pad)
    __shared__ float smallv[FIN + C1];   // wad | a_src
    __shared__ float part[4][256];       // as1 partials per cg per local node
    int t = threadIdx.x;

    // stage W: thread pair per row (8 float4 each)
    {
        int k = t >> 1, half = t & 1;
        const float4* src = reinterpret_cast<const float4*>(Ws + (size_t)k * C1);
        float4* dst = reinterpret_cast<float4*>(&Wt[k][0]);
        #pragma unroll
        for (int i = 0; i < 8; i++) dst[half * 8 + i] = src[half * 8 + i];
        if (t < FIN) smallv[t] = wad[t];
        if (t < C1) smallv[FIN + t] = a_src[t];
    }
    __syncthreads();

    int q = t & 63, cg = t >> 6;
    int nbase = blockIdx.x * 256 + q * 4;
    const float4* xr0 = reinterpret_cast<const float4*>(x + (size_t)(nbase + 0) * FIN);
    const float4* xr1 = reinterpret_cast<const float4*>(x + (size_t)(nbase + 1) * FIN);
    const float4* xr2 = reinterpret_cast<const float4*>(x + (size_t)(nbase + 2) * FIN);
    const float4* xr3 = reinterpret_cast<const float4*>(x + (size_t)(nbase + 3) * FIN);
    bool v0 = (nbase + 0) < NODES, v1 = (nbase + 1) < NODES;
    bool v2 = (nbase + 2) < NODES, v3 = (nbase + 3) < NODES;

    float acc[4][16];
    #pragma unroll
    for (int i = 0; i < 4; i++)
        #pragma unroll
        for (int c = 0; c < 16; c++) acc[i][c] = 0.f;
    float ad[4] = {0.f, 0.f, 0.f, 0.f};
    const float4 z4 = make_float4(0.f, 0.f, 0.f, 0.f);

    for (int kc = 0; kc < 32; kc++) {
        float4 xa = v0 ? xr0[kc] : z4;
        float4 xb = v1 ? xr1[kc] : z4;
        float4 xc = v2 ? xr2[kc] : z4;
        float4 xd = v3 ? xr3[kc] : z4;
        float xs0[4] = {xa.x, xa.y, xa.z, xa.w};
        float xs1[4] = {xb.x, xb.y, xb.z, xb.w};
        float xs2[4] = {xc.x, xc.y, xc.z, xc.w};
        float xs3[4] = {xd.x, xd.y, xd.z, xd.w};
        #pragma unroll
        for (int kk = 0; kk < 4; kk++) {
            int k = kc * 4 + kk;
            const float4* wr = reinterpret_cast<const float4*>(&Wt[k][cg * 16]);
            float4 w0 = wr[0], w1 = wr[1], w2 = wr[2], w3 = wr[3];
            float wv[16] = {w0.x, w0.y, w0.z, w0.w, w1.x, w1.y, w1.z, w1.w,
                            w2.x, w2.y, w2.z, w2.w, w3.x, w3.y, w3.z, w3.w};
            float k0 = xs0[kk], k1 = xs1[kk], k2 = xs2[kk], k3 = xs3[kk];
            #pragma unroll
            for (int c = 0; c < 16; c++) {
                acc[0][c] = fmaf(k0, wv[c], acc[0][c]);
                acc[1][c] = fmaf(k1, wv[c], acc[1][c]);
                acc[2][c] = fmaf(k2, wv[c], acc[2][c]);
                acc[3][c] = fmaf(k3, wv[c], acc[3][c]);
            }
            if (cg == 0) {
                float wk = smallv[k];
                ad[0] = fmaf(k0, wk, ad[0]);
                ad[1] = fmaf(k1, wk, ad[1]);
                ad[2] = fmaf(k2, wk, ad[2]);
                ad[3] = fmaf(k3, wk, ad[3]);
            }
        }
    }

    // as1 partials + hs writes
    #pragma unroll
    for (int i = 0; i < 4; i++) {
        float asp = 0.f;
        #pragma unroll
        for (int c = 0; c < 16; c++) asp = fmaf(acc[i][c], smallv[FIN + cg * 16 + c], asp);
        part[cg][q * 4 + i] = asp;
        if (nbase + i < NODES) {
            float4* hrow = reinterpret_cast<float4*>(hs + (size_t)(nbase + i) * C1 + cg * 16);
            #pragma unroll
            for (int j = 0; j < 4; j++)
                hrow[j] = make_float4(acc[i][j * 4], acc[i][j * 4 + 1], acc[i][j * 4 + 2], acc[i][j * 4 + 3]);
        }
    }
    __syncthreads();
    if (cg == 0) {
        #pragma unroll
        for (int i = 0; i < 4; i++) {
            int n = nbase + i;
            if (n < NODES) {
                int nl = q * 4 + i;
                as_out[n] = part[0][nl] + part[1][nl] + part[2][nl] + part[3][nl];
                ad_out[n] = ad[i];
            }
        }
    }
}

// ---------------- aggregation layer 1 ----------------
// wave per node; lane-parallel softmax (alpha = exp(e)/sum exp(e), max dropped
// algebraically; |e| <~ 12 << 88, clamp 60 as guard); 4x-unrolled row gathers.

__global__ __launch_bounds__(256) void k_agg1(const int* __restrict__ offs, const int* __restrict__ csr,
                                              const float* __restrict__ as1, const float* __restrict__ ad1,
                                              const float* __restrict__ hs1, const float* __restrict__ b1,
                                              float* __restrict__ h1) {
    int w = threadIdx.x >> 6, lane = threadIdx.x & 63;
    int node = blockIdx.x * 4 + w;
    if (node >= NODES) return;
    int e0 = offs[node], e1 = offs[node + 1];
    float adn = ad1[node];
    float acc0 = 0.f, acc1 = 0.f, acc2 = 0.f, acc3 = 0.f;
    float ssum = 0.f;
    for (int base = e0; base < e1; base += 64) {
        int cnt = e1 - base; if (cnt > 64) cnt = 64;
        bool valid = lane < cnt;
        int s = valid ? csr[base + lane] : 0;
        float v = valid ? (as1[s] + adn) : -INFINITY;
        v = v > 0.f ? v : NEG * v;
        float p = __expf(fminf(v, 60.f));
        ssum += p;
        int j = 0;
        for (; j + 4 <= cnt; j += 4) {
            int   s0 = __shfl(s, j),     s1 = __shfl(s, j + 1);
            int   s2 = __shfl(s, j + 2), s3 = __shfl(s, j + 3);
            float p0 = __shfl(p, j),     p1 = __shfl(p, j + 1);
            float p2 = __shfl(p, j + 2), p3 = __shfl(p, j + 3);
            acc0 = fmaf(p0, hs1[(size_t)s0 * C1 + lane], acc0);
            acc1 = fmaf(p1, hs1[(size_t)s1 * C1 + lane], acc1);
            acc2 = fmaf(p2, hs1[(size_t)s2 * C1 + lane], acc2);
            acc3 = fmaf(p3, hs1[(size_t)s3 * C1 + lane], acc3);
        }
        for (; j < cnt; j++) {
            int   sj = __shfl(s, j);
            float pj = __shfl(p, j);
            acc0 = fmaf(pj, hs1[(size_t)sj * C1 + lane], acc0);
        }
    }
    #pragma unroll
    for (int o = 32; o; o >>= 1) ssum += __shfl_xor(ssum, o);
    float acc = (acc0 + acc1) + (acc2 + acc3);
    h1[(size_t)node * C1 + lane] = acc / (ssum + 1e-16f) + b1[lane];
}

// ---------------- BN stats: deterministic per-block partials ----------------

__global__ __launch_bounds__(256) void k_bnstats(const float* __restrict__ h1, float* __restrict__ bnpart) {
    __shared__ float ls[256], lq[256];
    int t = threadIdx.x;
    int c = t & 63, g = t >> 6;
    float s = 0.f, q = 0.f;
    for (int n = blockIdx.x * 4 + g; n < NODES; n += BNBLK * 4) {
        float v = h1[(size_t)n * C1 + c];
        s += v;
        q = fmaf(v, v, q);
    }
    ls[t] = s; lq[t] = q;
    __syncthreads();
    if (t < 64) {
        bnpart[(size_t)blockIdx.x * 128 + t]      = ls[t] + ls[t + 64] + ls[t + 128] + ls[t + 192];
        bnpart[(size_t)blockIdx.x * 128 + 64 + t] = lq[t] + lq[t + 64] + lq[t + 128] + lq[t + 192];
    }
}

__global__ __launch_bounds__(64) void k_bnfinal(const float* __restrict__ bnpart,
                                                const float* __restrict__ gamma, const float* __restrict__ beta,
                                                float* bnscale, float* bnshift) {
    int c = threadIdx.x;
    if (c < C1) {
        float s = 0.f, q = 0.f;
        for (int b = 0; b < BNBLK; b++) {
            s += bnpart[(size_t)b * 128 + c];
            q += bnpart[(size_t)b * 128 + 64 + c];
        }
        float mu = s * (1.0f / NODES);
        float var = q * (1.0f / NODES) - mu * mu;
        if (var < 0.f) var = 0.f;
        float rinv = 1.0f / sqrtf(var + BNEPS);
        float sc = gamma[c] * rinv;
        bnscale[c] = sc;
        bnshift[c] = beta[c] - mu * sc;
    }
}

// ---------------- BN apply + ReLU + GEMM2 (+alpha dots) ----------------

__global__ __launch_bounds__(256) void k_bngemm2(const float* __restrict__ h1, const float* __restrict__ bnscale,
                                                 const float* __restrict__ bnshift, const float* __restrict__ W2s,
                                                 const float* __restrict__ wad2, const float* __restrict__ a2s,
                                                 float* __restrict__ hs2, float* __restrict__ as2,
                                                 float* __restrict__ ad2) {
    int n = blockIdx.x * 256 + threadIdx.x;
    if (n >= NODES) return;
    const float4* hr = reinterpret_cast<const float4*>(h1 + (size_t)n * C1);
    float h0 = 0.f, h1v = 0.f, adv = 0.f;
    #pragma unroll
    for (int c4 = 0; c4 < 16; c4++) {
        float4 v = hr[c4];
        float vv[4] = {v.x, v.y, v.z, v.w};
        #pragma unroll
        for (int j = 0; j < 4; j++) {
            int c = c4 * 4 + j;
            float y = fmaf(vv[j], bnscale[c], bnshift[c]);
            y = fmaxf(y, 0.f);
            h0 = fmaf(y, W2s[c * 2 + 0], h0);
            h1v = fmaf(y, W2s[c * 2 + 1], h1v);
            adv = fmaf(y, wad2[c], adv);
        }
    }
    hs2[n * 2 + 0] = h0;
    hs2[n * 2 + 1] = h1v;
    as2[n] = fmaf(h0, a2s[0], h1v * a2s[1]);
    ad2[n] = adv;
}

// ---------------- aggregation layer 2: wave per node, fully lane-parallel ----------------

__global__ __launch_bounds__(256) void k_agg2(const int* __restrict__ offs, const int* __restrict__ csr,
                                              const float* __restrict__ as2, const float* __restrict__ ad2,
                                              const float* __restrict__ hs2, const float* __restrict__ b2,
                                              float* __restrict__ out) {
    int w = threadIdx.x >> 6, lane = threadIdx.x & 63;
    int node = blockIdx.x * 4 + w;
    if (node >= NODES) return;
    int e0 = offs[node], e1 = offs[node + 1];
    float adn = ad2[node];
    float ssum = 0.f, A0 = 0.f, A1 = 0.f;
    const float2* h2 = reinterpret_cast<const float2*>(hs2);
    for (int base = e0; base < e1; base += 64) {
        int e = base + lane;
        bool valid = e < e1;
        int s = valid ? csr[e] : 0;
        float v = valid ? (as2[s] + adn) : -INFINITY;
        v = v > 0.f ? v : NEG * v;
        float p = __expf(fminf(v, 60.f));
        ssum += p;
        float2 hv = valid ? h2[s] : make_float2(0.f, 0.f);
        A0 = fmaf(p, hv.x, A0);
        A1 = fmaf(p, hv.y, A1);
    }
    #pragma unroll
    for (int o = 32; o; o >>= 1) {
        ssum += __shfl_xor(ssum, o);
        A0   += __shfl_xor(A0, o);
        A1   += __shfl_xor(A1, o);
    }
    if (lane == 0) {
        float inv = 1.0f / (ssum + 1e-16f);
        float2 r = make_float2(fmaf(A0, inv, b2[0]), fmaf(A1, inv, b2[1]));
        reinterpret_cast<float2*>(out)[node] = r;
    }
}

// ---------------- host ----------------

static inline size_t align256(size_t x) { return (x + 255) & ~size_t(255); }

extern "C" void kernel_launch(void* const* d_in, const int* in_sizes, int n_in,
                              void* d_out, int out_size, void* d_ws, size_t ws_size,
                              hipStream_t stream) {
    const float* x     = (const float*)d_in[0];
    const int*   ei    = (const int*)d_in[1];
    const float* W1s   = (const float*)d_in[2];
    const float* W1d   = (const float*)d_in[3];
    const float* a1s   = (const float*)d_in[4];
    const float* a1d   = (const float*)d_in[5];
    const float* b1    = (const float*)d_in[6];
    const float* gamma = (const float*)d_in[7];
    const float* beta  = (const float*)d_in[8];
    const float* W2s   = (const float*)d_in[9];
    const float* W2d   = (const float*)d_in[10];
    const float* a2s   = (const float*)d_in[11];
    const float* a2d   = (const float*)d_in[12];
    const float* b2    = (const float*)d_in[13];
    float* out = (float*)d_out;

    char* w = (char*)d_ws;
    size_t off = 0;
    auto alloc = [&](size_t bytes) -> void* {
        void* p = w + off;
        off = align256(off + bytes);
        return p;
    };
    int* offs     = (int*)alloc((size_t)(NODES + 1) * 4);
    int* bcur     = (int*)alloc(256 * 4);
    int* bbase    = (int*)alloc(256 * 4);
    int* csr      = (int*)alloc((size_t)ETOT * 4);
    float* hs1    = (float*)alloc((size_t)NODES * C1 * 4);
    float* as1    = (float*)alloc((size_t)NODES * 4);
    float* ad1    = (float*)alloc((size_t)NODES * 4);
    float* h1     = (float*)alloc((size_t)NODES * C1 * 4);   // also aliases csr_tmp (see below)
    float* hs2    = (float*)alloc((size_t)NODES * 2 * 4);
    float* as2    = (float*)alloc((size_t)NODES * 4);
    float* ad2    = (float*)alloc((size_t)NODES * 4);
    float* wad1   = (float*)alloc(FIN * 4);
    float* wad2   = (float*)alloc(C1 * 4);
    float* bnpart = (float*)alloc((size_t)BNBLK * 128 * 4);
    float* bnsc   = (float*)alloc(64 * 4);
    float* bnsh   = (float*)alloc(64 * 4);
    if (off > ws_size) return;

    // csr_tmp (NBUCK*PCAP ints = 9.7MB) aliases h1 (25.6MB): k_build fully consumes
    // csr_tmp before k_agg1 produces h1 (in-order stream => safe).
    unsigned* csr_tmp = (unsigned*)h1;

    k_zero256<<<1, 256, 0, stream>>>(bcur);
    k_part<<<(NEDGE + PTILE - 1) / PTILE, 256, 0, stream>>>(ei, bcur, csr_tmp);
    k_bscan<<<1, 256, 0, stream>>>(bcur, bbase);
    k_build<<<NBUCK, 256, 0, stream>>>(csr_tmp, bcur, bbase, offs, csr);
    k_prep<<<1, 128, 0, stream>>>(W1d, a1d, W2d, a2d, wad1, wad2);
    k_gemm1<<<(NODES + 255) / 256, 256, 0, stream>>>(x, W1s, wad1, a1s, hs1, as1, ad1);
    k_agg1<<<(NODES + 3) / 4, 256, 0, stream>>>(offs, csr, as1, ad1, hs1, b1, h1);
    k_bnstats<<<BNBLK, 256, 0, stream>>>(h1, bnpart);
    k_bnfinal<<<1, 64, 0, stream>>>(bnpart, gamma, beta, bnsc, bnsh);
    k_bngemm2<<<(NODES + 255) / 256, 256, 0, stream>>>(h1, bnsc, bnsh, W2s, wad2, a2s, hs2, as2, ad2);
    k_agg2<<<(NODES + 3) / 4, 256, 0, stream>>>(offs, csr, as2, ad2, hs2, b2, out);
}

// Round 7
// 229.976 us; speedup vs baseline: 1.3660x; 1.3660x over previous
//
#include <hip/hip_runtime.h>
#include <math.h>

#define NODES 100000
#define NEDGE 1600000
#define ETOT  (NEDGE + NODES)
#define FIN   128
#define C1    64
#define NEG   0.2f
#define BNEPS 1e-5f
#define BNBLK 256

#define BK     512                         // nodes per bucket
#define NBUCK  ((NODES + BK - 1) / BK)     // 196
#define PCAP   12288                       // per-bucket edge capacity (mean 8673, +38 sigma)
#define PTILE  4096                        // edges per k_part block

// ---------------- bucketed CSR build ----------------

__global__ __launch_bounds__(256) void k_zero256(int* p) {
    p[threadIdx.x] = 0;
}

// P1: partition edges into buckets by dst>>9; pack src | (dst&511)<<17
__global__ __launch_bounds__(256) void k_part(const int* __restrict__ ei, int* bcur,
                                              unsigned* __restrict__ tmp) {
    __shared__ int hist[256], hbase[256], run[256];
    int t = threadIdx.x;
    hist[t] = 0; run[t] = 0;
    __syncthreads();
    const int* srcs = ei;
    const int* dsts = ei + NEDGE;
    int e_base = blockIdx.x * PTILE;
    unsigned pack[16];
    int bkt[16];
    #pragma unroll
    for (int i = 0; i < 16; i++) {
        int e = e_base + i * 256 + t;
        bool valid = e < NEDGE;
        int s = valid ? srcs[e] : 0;
        int d = valid ? dsts[e] : 0;
        if ((unsigned)d >= NODES || (unsigned)s >= NODES) valid = false;
        bkt[i] = valid ? (d >> 9) : -1;
        pack[i] = (unsigned)s | ((unsigned)(d & (BK - 1)) << 17);
        if (valid) atomicAdd(&hist[bkt[i]], 1);
    }
    __syncthreads();
    hbase[t] = hist[t] ? atomicAdd(&bcur[t], hist[t]) : 0;
    __syncthreads();
    #pragma unroll
    for (int i = 0; i < 16; i++) {
        if (bkt[i] >= 0) {
            int slot = atomicAdd(&run[bkt[i]], 1) + hbase[bkt[i]];
            if (slot < PCAP) tmp[(size_t)bkt[i] * PCAP + slot] = pack[i];
        }
    }
}

// exclusive scan of 256 bucket totals
__global__ __launch_bounds__(256) void k_bscan(const int* __restrict__ bcur, int* __restrict__ bbase) {
    __shared__ int lds[256];
    int t = threadIdx.x;
    int own = bcur[t];
    lds[t] = own;
    __syncthreads();
    for (int o = 1; o < 256; o <<= 1) {
        int add = (t >= o) ? lds[t - o] : 0;
        __syncthreads();
        lds[t] += add;
        __syncthreads();
    }
    bbase[t] = lds[t] - own;
}

// P2: per bucket: per-node counts -> local scan (offs) -> LDS scatter -> coalesced csr write
__global__ __launch_bounds__(256) void k_build(const unsigned* __restrict__ tmp, const int* __restrict__ bcur,
                                               const int* __restrict__ bbase, int* __restrict__ offs,
                                               int* __restrict__ csr) {
    __shared__ int cnt[BK];        // per-node edge count, then cursor
    __shared__ int ps[256];        // pair-sum scan
    __shared__ int stage[PCAP + BK];
    int t = threadIdx.x;
    int b = blockIdx.x;
    int ecnt = bcur[b]; if (ecnt > PCAP) ecnt = PCAP;
    int csrbase = bbase[b] + BK * b;   // all earlier buckets have BK valid nodes (self-loops)
    const unsigned* ebuf = tmp + (size_t)b * PCAP;

    cnt[t] = 0; cnt[t + 256] = 0;
    __syncthreads();
    for (int e = t; e < ecnt; e += 256) {
        int dl = (ebuf[e] >> 17) & (BK - 1);
        atomicAdd(&cnt[dl], 1);
    }
    __syncthreads();
    // local exclusive scan over 512 counts (+1 self-loop per valid node)
    int i0 = 2 * t, i1 = 2 * t + 1;
    int g0 = b * BK + i0, g1 = b * BK + i1;
    int c0 = cnt[i0] + (g0 < NODES ? 1 : 0);
    int c1 = cnt[i1] + (g1 < NODES ? 1 : 0);
    int own = c0 + c1;
    ps[t] = own;
    __syncthreads();
    for (int o = 1; o < 256; o <<= 1) {
        int add = (t >= o) ? ps[t - o] : 0;
        __syncthreads();
        ps[t] += add;
        __syncthreads();
    }
    int excl0 = ps[t] - own;
    int excl1 = excl0 + c0;
    int total = ps[255];
    __syncthreads();
    // cursors + self-loops + offs
    if (g0 < NODES) {
        stage[excl0] = g0;
        cnt[i0] = excl0 + 1;
        offs[g0] = csrbase + excl0;
    }
    if (g1 < NODES) {
        stage[excl1] = g1;
        cnt[i1] = excl1 + 1;
        offs[g1] = csrbase + excl1;
    }
    if (b == NBUCK - 1 && t == 0) offs[NODES] = ETOT;
    __syncthreads();
    for (int e = t; e < ecnt; e += 256) {
        unsigned p = ebuf[e];
        int dl = (p >> 17) & (BK - 1);
        int slot = atomicAdd(&cnt[dl], 1);
        stage[slot] = (int)(p & 0x1FFFFu);
    }
    __syncthreads();
    for (int j = t; j < total; j += 256) csr[csrbase + j] = stage[j];
}

// ---------------- small precomputed vectors ----------------

__global__ __launch_bounds__(128) void k_prep(const float* __restrict__ W1d, const float* __restrict__ a1d,
                                              const float* __restrict__ W2d, const float* __restrict__ a2d,
                                              float* wad1, float* wad2) {
    int t = threadIdx.x;
    if (t < FIN) {
        float acc = 0.f;
        for (int c = 0; c < C1; c++) acc = fmaf(W1d[t * C1 + c], a1d[c], acc);
        wad1[t] = acc;
    }
    if (t < C1) {
        wad2[t] = fmaf(W2d[t * 2], a2d[0], W2d[t * 2 + 1] * a2d[1]);
    }
}

// ---------------- GEMM1: hs1 = x@W1_src, ad1 = x@wad1, as1 = hs1@a1_src ----------------
// lane = node (64/block), wave = 16-channel group. x tile in LDS (only LDS user, 4 blk/CU).
// W read via WAVE-UNIFORM addresses (cg forced uniform with readfirstlane) -> scalar
// s_load path through the scalar cache: no VALU cost, no vector-L1 pollution from x.
// Inner loop per k: 16 FMA + 16 scalar floats; per k4: one ds_read_b128 for x.

__global__ __launch_bounds__(256) void k_gemm1(const float* __restrict__ x, const float* __restrict__ Ws,
                                               const float* __restrict__ wad, const float* __restrict__ a_src,
                                               float* __restrict__ hs, float* __restrict__ as_out,
                                               float* __restrict__ ad_out) {
    __shared__ float4 xs[64 * 33];     // 33.8 KB
    __shared__ float  part[4][64];
    int t = threadIdx.x;
    int lane = t & 63;
    int cg = __builtin_amdgcn_readfirstlane(t >> 6);   // wave-uniform channel group
    int n0 = blockIdx.x * 64;

    // stage x tile, 64B-coalesced: thread quad (q=t&3) covers consecutive float4s
    {
        int node_l = t >> 2, q = t & 3;
        bool v = (n0 + node_l) < NODES;
        const float4* xr = reinterpret_cast<const float4*>(x + (size_t)(n0 + node_l) * FIN);
        #pragma unroll
        for (int i = 0; i < 8; i++) {
            int j = i * 4 + q;
            xs[node_l * 33 + j] = v ? xr[j] : make_float4(0.f, 0.f, 0.f, 0.f);
        }
    }
    __syncthreads();

    const float* __restrict__ Wcg = Ws + cg * 16;     // uniform base (SGPR)
    float acc[16];
    #pragma unroll
    for (int c = 0; c < 16; c++) acc[c] = 0.f;
    float adacc = 0.f;

    for (int k4 = 0; k4 < 32; k4++) {
        float4 xv = xs[lane * 33 + k4];
        float xk[4] = {xv.x, xv.y, xv.z, xv.w};
        #pragma unroll
        for (int kk = 0; kk < 4; kk++) {
            int k = k4 * 4 + kk;
            const float* __restrict__ wr = Wcg + (size_t)k * C1;   // uniform -> s_load
            #pragma unroll
            for (int c = 0; c < 16; c++) acc[c] = fmaf(xk[kk], wr[c], acc[c]);
            if (cg == 0) adacc = fmaf(xk[kk], wad[k], adacc);
        }
    }

    float asp = 0.f;
    #pragma unroll
    for (int c = 0; c < 16; c++) asp = fmaf(acc[c], a_src[cg * 16 + c], asp);
    part[cg][lane] = asp;
    int n = n0 + lane;
    if (n < NODES) {
        float4* hrow = reinterpret_cast<float4*>(hs + (size_t)n * C1 + cg * 16);
        #pragma unroll
        for (int i = 0; i < 4; i++)
            hrow[i] = make_float4(acc[i * 4], acc[i * 4 + 1], acc[i * 4 + 2], acc[i * 4 + 3]);
    }
    __syncthreads();
    if (cg == 0 && n < NODES) {
        as_out[n] = part[0][lane] + part[1][lane] + part[2][lane] + part[3][lane];
        ad_out[n] = adacc;
    }
}

// ---------------- aggregation layer 1 ----------------
// wave per node; lane-parallel softmax (alpha = exp(e)/sum exp(e), max dropped
// algebraically; |e| <~ 12 << 88, clamp 60 as guard); 4x-unrolled row gathers.

__global__ __launch_bounds__(256) void k_agg1(const int* __restrict__ offs, const int* __restrict__ csr,
                                              const float* __restrict__ as1, const float* __restrict__ ad1,
                                              const float* __restrict__ hs1, const float* __restrict__ b1,
                                              float* __restrict__ h1) {
    int w = threadIdx.x >> 6, lane = threadIdx.x & 63;
    int node = blockIdx.x * 4 + w;
    if (node >= NODES) return;
    int e0 = offs[node], e1 = offs[node + 1];
    float adn = ad1[node];
    float acc0 = 0.f, acc1 = 0.f, acc2 = 0.f, acc3 = 0.f;
    float ssum = 0.f;
    for (int base = e0; base < e1; base += 64) {
        int cnt = e1 - base; if (cnt > 64) cnt = 64;
        bool valid = lane < cnt;
        int s = valid ? csr[base + lane] : 0;
        float v = valid ? (as1[s] + adn) : -INFINITY;
        v = v > 0.f ? v : NEG * v;
        float p = __expf(fminf(v, 60.f));
        ssum += p;
        int j = 0;
        for (; j + 4 <= cnt; j += 4) {
            int   s0 = __shfl(s, j),     s1 = __shfl(s, j + 1);
            int   s2 = __shfl(s, j + 2), s3 = __shfl(s, j + 3);
            float p0 = __shfl(p, j),     p1 = __shfl(p, j + 1);
            float p2 = __shfl(p, j + 2), p3 = __shfl(p, j + 3);
            acc0 = fmaf(p0, hs1[(size_t)s0 * C1 + lane], acc0);
            acc1 = fmaf(p1, hs1[(size_t)s1 * C1 + lane], acc1);
            acc2 = fmaf(p2, hs1[(size_t)s2 * C1 + lane], acc2);
            acc3 = fmaf(p3, hs1[(size_t)s3 * C1 + lane], acc3);
        }
        for (; j < cnt; j++) {
            int   sj = __shfl(s, j);
            float pj = __shfl(p, j);
            acc0 = fmaf(pj, hs1[(size_t)sj * C1 + lane], acc0);
        }
    }
    #pragma unroll
    for (int o = 32; o; o >>= 1) ssum += __shfl_xor(ssum, o);
    float acc = (acc0 + acc1) + (acc2 + acc3);
    h1[(size_t)node * C1 + lane] = acc / (ssum + 1e-16f) + b1[lane];
}

// ---------------- BN stats: deterministic per-block partials ----------------

__global__ __launch_bounds__(256) void k_bnstats(const float* __restrict__ h1, float* __restrict__ bnpart) {
    __shared__ float ls[256], lq[256];
    int t = threadIdx.x;
    int c = t & 63, g = t >> 6;
    float s = 0.f, q = 0.f;
    for (int n = blockIdx.x * 4 + g; n < NODES; n += BNBLK * 4) {
        float v = h1[(size_t)n * C1 + c];
        s += v;
        q = fmaf(v, v, q);
    }
    ls[t] = s; lq[t] = q;
    __syncthreads();
    if (t < 64) {
        bnpart[(size_t)blockIdx.x * 128 + t]      = ls[t] + ls[t + 64] + ls[t + 128] + ls[t + 192];
        bnpart[(size_t)blockIdx.x * 128 + 64 + t] = lq[t] + lq[t + 64] + lq[t + 128] + lq[t + 192];
    }
}

__global__ __launch_bounds__(64) void k_bnfinal(const float* __restrict__ bnpart,
                                                const float* __restrict__ gamma, const float* __restrict__ beta,
                                                float* bnscale, float* bnshift) {
    int c = threadIdx.x;
    if (c < C1) {
        float s = 0.f, q = 0.f;
        for (int b = 0; b < BNBLK; b++) {
            s += bnpart[(size_t)b * 128 + c];
            q += bnpart[(size_t)b * 128 + 64 + c];
        }
        float mu = s * (1.0f / NODES);
        float var = q * (1.0f / NODES) - mu * mu;
        if (var < 0.f) var = 0.f;
        float rinv = 1.0f / sqrtf(var + BNEPS);
        float sc = gamma[c] * rinv;
        bnscale[c] = sc;
        bnshift[c] = beta[c] - mu * sc;
    }
}

// ---------------- BN apply + ReLU + GEMM2 (+alpha dots) ----------------

__global__ __launch_bounds__(256) void k_bngemm2(const float* __restrict__ h1, const float* __restrict__ bnscale,
                                                 const float* __restrict__ bnshift, const float* __restrict__ W2s,
                                                 const float* __restrict__ wad2, const float* __restrict__ a2s,
                                                 float* __restrict__ hs2, float* __restrict__ as2,
                                                 float* __restrict__ ad2) {
    int n = blockIdx.x * 256 + threadIdx.x;
    if (n >= NODES) return;
    const float4* hr = reinterpret_cast<const float4*>(h1 + (size_t)n * C1);
    float h0 = 0.f, h1v = 0.f, adv = 0.f;
    #pragma unroll
    for (int c4 = 0; c4 < 16; c4++) {
        float4 v = hr[c4];
        float vv[4] = {v.x, v.y, v.z, v.w};
        #pragma unroll
        for (int j = 0; j < 4; j++) {
            int c = c4 * 4 + j;
            float y = fmaf(vv[j], bnscale[c], bnshift[c]);
            y = fmaxf(y, 0.f);
            h0 = fmaf(y, W2s[c * 2 + 0], h0);
            h1v = fmaf(y, W2s[c * 2 + 1], h1v);
            adv = fmaf(y, wad2[c], adv);
        }
    }
    hs2[n * 2 + 0] = h0;
    hs2[n * 2 + 1] = h1v;
    as2[n] = fmaf(h0, a2s[0], h1v * a2s[1]);
    ad2[n] = adv;
}

// ---------------- aggregation layer 2: wave per node, fully lane-parallel ----------------

__global__ __launch_bounds__(256) void k_agg2(const int* __restrict__ offs, const int* __restrict__ csr,
                                              const float* __restrict__ as2, const float* __restrict__ ad2,
                                              const float* __restrict__ hs2, const float* __restrict__ b2,
                                              float* __restrict__ out) {
    int w = threadIdx.x >> 6, lane = threadIdx.x & 63;
    int node = blockIdx.x * 4 + w;
    if (node >= NODES) return;
    int e0 = offs[node], e1 = offs[node + 1];
    float adn = ad2[node];
    float ssum = 0.f, A0 = 0.f, A1 = 0.f;
    const float2* h2 = reinterpret_cast<const float2*>(hs2);
    for (int base = e0; base < e1; base += 64) {
        int e = base + lane;
        bool valid = e < e1;
        int s = valid ? csr[e] : 0;
        float v = valid ? (as2[s] + adn) : -INFINITY;
        v = v > 0.f ? v : NEG * v;
        float p = __expf(fminf(v, 60.f));
        ssum += p;
        float2 hv = valid ? h2[s] : make_float2(0.f, 0.f);
        A0 = fmaf(p, hv.x, A0);
        A1 = fmaf(p, hv.y, A1);
    }
    #pragma unroll
    for (int o = 32; o; o >>= 1) {
        ssum += __shfl_xor(ssum, o);
        A0   += __shfl_xor(A0, o);
        A1   += __shfl_xor(A1, o);
    }
    if (lane == 0) {
        float inv = 1.0f / (ssum + 1e-16f);
        float2 r = make_float2(fmaf(A0, inv, b2[0]), fmaf(A1, inv, b2[1]));
        reinterpret_cast<float2*>(out)[node] = r;
    }
}

// ---------------- host ----------------

static inline size_t align256(size_t x) { return (x + 255) & ~size_t(255); }

extern "C" void kernel_launch(void* const* d_in, const int* in_sizes, int n_in,
                              void* d_out, int out_size, void* d_ws, size_t ws_size,
                              hipStream_t stream) {
    const float* x     = (const float*)d_in[0];
    const int*   ei    = (const int*)d_in[1];
    const float* W1s   = (const float*)d_in[2];
    const float* W1d   = (const float*)d_in[3];
    const float* a1s   = (const float*)d_in[4];
    const float* a1d   = (const float*)d_in[5];
    const float* b1    = (const float*)d_in[6];
    const float* gamma = (const float*)d_in[7];
    const float* beta  = (const float*)d_in[8];
    const float* W2s   = (const float*)d_in[9];
    const float* W2d   = (const float*)d_in[10];
    const float* a2s   = (const float*)d_in[11];
    const float* a2d   = (const float*)d_in[12];
    const float* b2    = (const float*)d_in[13];
    float* out = (float*)d_out;

    char* w = (char*)d_ws;
    size_t off = 0;
    auto alloc = [&](size_t bytes) -> void* {
        void* p = w + off;
        off = align256(off + bytes);
        return p;
    };
    int* offs     = (int*)alloc((size_t)(NODES + 1) * 4);
    int* bcur     = (int*)alloc(256 * 4);
    int* bbase    = (int*)alloc(256 * 4);
    int* csr      = (int*)alloc((size_t)ETOT * 4);
    float* hs1    = (float*)alloc((size_t)NODES * C1 * 4);
    float* as1    = (float*)alloc((size_t)NODES * 4);
    float* ad1    = (float*)alloc((size_t)NODES * 4);
    float* h1     = (float*)alloc((size_t)NODES * C1 * 4);   // also aliases csr_tmp (see below)
    float* hs2    = (float*)alloc((size_t)NODES * 2 * 4);
    float* as2    = (float*)alloc((size_t)NODES * 4);
    float* ad2    = (float*)alloc((size_t)NODES * 4);
    float* wad1   = (float*)alloc(FIN * 4);
    float* wad2   = (float*)alloc(C1 * 4);
    float* bnpart = (float*)alloc((size_t)BNBLK * 128 * 4);
    float* bnsc   = (float*)alloc(64 * 4);
    float* bnsh   = (float*)alloc(64 * 4);
    if (off > ws_size) return;

    // csr_tmp (NBUCK*PCAP ints = 9.7MB) aliases h1 (25.6MB): k_build fully consumes
    // csr_tmp before k_agg1 produces h1 (in-order stream => safe).
    unsigned* csr_tmp = (unsigned*)h1;

    k_zero256<<<1, 256, 0, stream>>>(bcur);
    k_part<<<(NEDGE + PTILE - 1) / PTILE, 256, 0, stream>>>(ei, bcur, csr_tmp);
    k_bscan<<<1, 256, 0, stream>>>(bcur, bbase);
    k_build<<<NBUCK, 256, 0, stream>>>(csr_tmp, bcur, bbase, offs, csr);
    k_prep<<<1, 128, 0, stream>>>(W1d, a1d, W2d, a2d, wad1, wad2);
    k_gemm1<<<(NODES + 63) / 64, 256, 0, stream>>>(x, W1s, wad1, a1s, hs1, as1, ad1);
    k_agg1<<<(NODES + 3) / 4, 256, 0, stream>>>(offs, csr, as1, ad1, hs1, b1, h1);
    k_bnstats<<<BNBLK, 256, 0, stream>>>(h1, bnpart);
    k_bnfinal<<<1, 64, 0, stream>>>(bnpart, gamma, beta, bnsc, bnsh);
    k_bngemm2<<<(NODES + 255) / 256, 256, 0, stream>>>(h1, bnsc, bnsh, W2s, wad2, a2s, hs2, as2, ad2);
    k_agg2<<<(NODES + 3) / 4, 256, 0, stream>>>(offs, csr, as2, ad2, hs2, b2, out);
}

// Round 8
// 219.121 us; speedup vs baseline: 1.4337x; 1.0495x over previous
//
#include <hip/hip_runtime.h>
#include <hip/hip_fp16.h>
#include <math.h>

#define NODES 100000
#define NEDGE 1600000
#define ETOT  (NEDGE + NODES)
#define FIN   128
#define C1    64
#define NEG   0.2f
#define BNEPS 1e-5f
#define BNBLK 256

#define BK     512                         // nodes per bucket
#define NBUCK  ((NODES + BK - 1) / BK)     // 196
#define PCAP   12288                       // per-bucket edge capacity (mean 8673, +38 sigma)
#define PTILE  4096                        // edges per k_part block

// ---------------- bucketed CSR build ----------------

__global__ __launch_bounds__(256) void k_zero256(int* p) {
    p[threadIdx.x] = 0;
}

// P1: partition edges into buckets by dst>>9; pack src | (dst&511)<<17
__global__ __launch_bounds__(256) void k_part(const int* __restrict__ ei, int* bcur,
                                              unsigned* __restrict__ tmp) {
    __shared__ int hist[256], hbase[256], run[256];
    int t = threadIdx.x;
    hist[t] = 0; run[t] = 0;
    __syncthreads();
    const int* srcs = ei;
    const int* dsts = ei + NEDGE;
    int e_base = blockIdx.x * PTILE;
    unsigned pack[16];
    int bkt[16];
    #pragma unroll
    for (int i = 0; i < 16; i++) {
        int e = e_base + i * 256 + t;
        bool valid = e < NEDGE;
        int s = valid ? srcs[e] : 0;
        int d = valid ? dsts[e] : 0;
        if ((unsigned)d >= NODES || (unsigned)s >= NODES) valid = false;
        bkt[i] = valid ? (d >> 9) : -1;
        pack[i] = (unsigned)s | ((unsigned)(d & (BK - 1)) << 17);
        if (valid) atomicAdd(&hist[bkt[i]], 1);
    }
    __syncthreads();
    hbase[t] = hist[t] ? atomicAdd(&bcur[t], hist[t]) : 0;
    __syncthreads();
    #pragma unroll
    for (int i = 0; i < 16; i++) {
        if (bkt[i] >= 0) {
            int slot = atomicAdd(&run[bkt[i]], 1) + hbase[bkt[i]];
            if (slot < PCAP) tmp[(size_t)bkt[i] * PCAP + slot] = pack[i];
        }
    }
}

// exclusive scan of 256 bucket totals
__global__ __launch_bounds__(256) void k_bscan(const int* __restrict__ bcur, int* __restrict__ bbase) {
    __shared__ int lds[256];
    int t = threadIdx.x;
    int own = bcur[t];
    lds[t] = own;
    __syncthreads();
    for (int o = 1; o < 256; o <<= 1) {
        int add = (t >= o) ? lds[t - o] : 0;
        __syncthreads();
        lds[t] += add;
        __syncthreads();
    }
    bbase[t] = lds[t] - own;
}

// P2: per bucket: per-node counts -> local scan (offs) -> LDS scatter -> coalesced csr write
__global__ __launch_bounds__(256) void k_build(const unsigned* __restrict__ tmp, const int* __restrict__ bcur,
                                               const int* __restrict__ bbase, int* __restrict__ offs,
                                               int* __restrict__ csr) {
    __shared__ int cnt[BK];        // per-node edge count, then cursor
    __shared__ int ps[256];        // pair-sum scan
    __shared__ int stage[PCAP + BK];
    int t = threadIdx.x;
    int b = blockIdx.x;
    int ecnt = bcur[b]; if (ecnt > PCAP) ecnt = PCAP;
    int csrbase = bbase[b] + BK * b;   // all earlier buckets have BK valid nodes (self-loops)
    const unsigned* ebuf = tmp + (size_t)b * PCAP;

    cnt[t] = 0; cnt[t + 256] = 0;
    __syncthreads();
    for (int e = t; e < ecnt; e += 256) {
        int dl = (ebuf[e] >> 17) & (BK - 1);
        atomicAdd(&cnt[dl], 1);
    }
    __syncthreads();
    // local exclusive scan over 512 counts (+1 self-loop per valid node)
    int i0 = 2 * t, i1 = 2 * t + 1;
    int g0 = b * BK + i0, g1 = b * BK + i1;
    int c0 = cnt[i0] + (g0 < NODES ? 1 : 0);
    int c1 = cnt[i1] + (g1 < NODES ? 1 : 0);
    int own = c0 + c1;
    ps[t] = own;
    __syncthreads();
    for (int o = 1; o < 256; o <<= 1) {
        int add = (t >= o) ? ps[t - o] : 0;
        __syncthreads();
        ps[t] += add;
        __syncthreads();
    }
    int excl0 = ps[t] - own;
    int excl1 = excl0 + c0;
    int total = ps[255];
    __syncthreads();
    // cursors + self-loops + offs
    if (g0 < NODES) {
        stage[excl0] = g0;
        cnt[i0] = excl0 + 1;
        offs[g0] = csrbase + excl0;
    }
    if (g1 < NODES) {
        stage[excl1] = g1;
        cnt[i1] = excl1 + 1;
        offs[g1] = csrbase + excl1;
    }
    if (b == NBUCK - 1 && t == 0) offs[NODES] = ETOT;
    __syncthreads();
    for (int e = t; e < ecnt; e += 256) {
        unsigned p = ebuf[e];
        int dl = (p >> 17) & (BK - 1);
        int slot = atomicAdd(&cnt[dl], 1);
        stage[slot] = (int)(p & 0x1FFFFu);
    }
    __syncthreads();
    for (int j = t; j < total; j += 256) csr[csrbase + j] = stage[j];
}

// ---------------- small precomputed vectors ----------------

__global__ __launch_bounds__(128) void k_prep(const float* __restrict__ W1d, const float* __restrict__ a1d,
                                              const float* __restrict__ W2d, const float* __restrict__ a2d,
                                              float* wad1, float* wad2) {
    int t = threadIdx.x;
    if (t < FIN) {
        float acc = 0.f;
        for (int c = 0; c < C1; c++) acc = fmaf(W1d[t * C1 + c], a1d[c], acc);
        wad1[t] = acc;
    }
    if (t < C1) {
        wad2[t] = fmaf(W2d[t * 2], a2d[0], W2d[t * 2 + 1] * a2d[1]);
    }
}

// ---------------- GEMM1: hs1(fp16) = x@W1_src, ad1 = x@wad1, as1 = hs1@a1_src ----------------
// lane = node (64/block), wave = 16-channel group. x tile in LDS; W via wave-uniform
// scalar loads (scalar cache). hs1 stored as fp16 (halves agg1's gather bytes);
// as1 computed from fp32 accumulators in-register (no precision loss).

__global__ __launch_bounds__(256) void k_gemm1(const float* __restrict__ x, const float* __restrict__ Ws,
                                               const float* __restrict__ wad, const float* __restrict__ a_src,
                                               __half* __restrict__ hsh, float* __restrict__ as_out,
                                               float* __restrict__ ad_out) {
    __shared__ float4 xs[64 * 33];     // 33.8 KB
    __shared__ float  part[4][64];
    int t = threadIdx.x;
    int lane = t & 63;
    int cg = __builtin_amdgcn_readfirstlane(t >> 6);   // wave-uniform channel group
    int n0 = blockIdx.x * 64;

    // stage x tile, 64B-coalesced: thread quad (q=t&3) covers consecutive float4s
    {
        int node_l = t >> 2, q = t & 3;
        bool v = (n0 + node_l) < NODES;
        const float4* xr = reinterpret_cast<const float4*>(x + (size_t)(n0 + node_l) * FIN);
        #pragma unroll
        for (int i = 0; i < 8; i++) {
            int j = i * 4 + q;
            xs[node_l * 33 + j] = v ? xr[j] : make_float4(0.f, 0.f, 0.f, 0.f);
        }
    }
    __syncthreads();

    const float* __restrict__ Wcg = Ws + cg * 16;     // uniform base (SGPR)
    float acc[16];
    #pragma unroll
    for (int c = 0; c < 16; c++) acc[c] = 0.f;
    float adacc = 0.f;

    for (int k4 = 0; k4 < 32; k4++) {
        float4 xv = xs[lane * 33 + k4];
        float xk[4] = {xv.x, xv.y, xv.z, xv.w};
        #pragma unroll
        for (int kk = 0; kk < 4; kk++) {
            int k = k4 * 4 + kk;
            const float* __restrict__ wr = Wcg + (size_t)k * C1;   // uniform -> s_load
            #pragma unroll
            for (int c = 0; c < 16; c++) acc[c] = fmaf(xk[kk], wr[c], acc[c]);
            if (cg == 0) adacc = fmaf(xk[kk], wad[k], adacc);
        }
    }

    float asp = 0.f;
    #pragma unroll
    for (int c = 0; c < 16; c++) asp = fmaf(acc[c], a_src[cg * 16 + c], asp);
    part[cg][lane] = asp;
    int n = n0 + lane;
    if (n < NODES) {
        // pack 16 fp32 -> 16 fp16 -> two uint4 stores (32B)
        unsigned pk[8];
        #pragma unroll
        for (int j = 0; j < 8; j++) {
            __half2 h2 = __floats2half2_rn(acc[2 * j], acc[2 * j + 1]);
            pk[j] = *reinterpret_cast<unsigned*>(&h2);
        }
        uint4* dst = reinterpret_cast<uint4*>(hsh + (size_t)n * C1 + cg * 16);
        dst[0] = make_uint4(pk[0], pk[1], pk[2], pk[3]);
        dst[1] = make_uint4(pk[4], pk[5], pk[6], pk[7]);
    }
    __syncthreads();
    if (cg == 0 && n < NODES) {
        as_out[n] = part[0][lane] + part[1][lane] + part[2][lane] + part[3][lane];
        ad_out[n] = adacc;
    }
}

// ---------------- aggregation layer 1 ----------------
// wave per node; lane-parallel softmax (alpha = exp(e)/sum exp(e), max dropped
// algebraically; |e| <~ 12 << 88, clamp 60 as guard); 4x-unrolled fp16 row gathers.

__global__ __launch_bounds__(256) void k_agg1(const int* __restrict__ offs, const int* __restrict__ csr,
                                              const float* __restrict__ as1, const float* __restrict__ ad1,
                                              const __half* __restrict__ hsh, const float* __restrict__ b1,
                                              float* __restrict__ h1) {
    int w = threadIdx.x >> 6, lane = threadIdx.x & 63;
    int node = blockIdx.x * 4 + w;
    if (node >= NODES) return;
    int e0 = offs[node], e1 = offs[node + 1];
    float adn = ad1[node];
    float acc0 = 0.f, acc1 = 0.f, acc2 = 0.f, acc3 = 0.f;
    float ssum = 0.f;
    for (int base = e0; base < e1; base += 64) {
        int cnt = e1 - base; if (cnt > 64) cnt = 64;
        bool valid = lane < cnt;
        int s = valid ? csr[base + lane] : 0;
        float v = valid ? (as1[s] + adn) : -INFINITY;
        v = v > 0.f ? v : NEG * v;
        float p = __expf(fminf(v, 60.f));
        ssum += p;
        int j = 0;
        for (; j + 4 <= cnt; j += 4) {
            int   s0 = __shfl(s, j),     s1 = __shfl(s, j + 1);
            int   s2 = __shfl(s, j + 2), s3 = __shfl(s, j + 3);
            float p0 = __shfl(p, j),     p1 = __shfl(p, j + 1);
            float p2 = __shfl(p, j + 2), p3 = __shfl(p, j + 3);
            acc0 = fmaf(p0, __half2float(hsh[(size_t)s0 * C1 + lane]), acc0);
            acc1 = fmaf(p1, __half2float(hsh[(size_t)s1 * C1 + lane]), acc1);
            acc2 = fmaf(p2, __half2float(hsh[(size_t)s2 * C1 + lane]), acc2);
            acc3 = fmaf(p3, __half2float(hsh[(size_t)s3 * C1 + lane]), acc3);
        }
        for (; j < cnt; j++) {
            int   sj = __shfl(s, j);
            float pj = __shfl(p, j);
            acc0 = fmaf(pj, __half2float(hsh[(size_t)sj * C1 + lane]), acc0);
        }
    }
    #pragma unroll
    for (int o = 32; o; o >>= 1) ssum += __shfl_xor(ssum, o);
    float acc = (acc0 + acc1) + (acc2 + acc3);
    h1[(size_t)node * C1 + lane] = acc / (ssum + 1e-16f) + b1[lane];
}

// ---------------- BN stats: deterministic per-block partials ----------------

__global__ __launch_bounds__(256) void k_bnstats(const float* __restrict__ h1, float* __restrict__ bnpart) {
    __shared__ float ls[256], lq[256];
    int t = threadIdx.x;
    int c = t & 63, g = t >> 6;
    float s = 0.f, q = 0.f;
    for (int n = blockIdx.x * 4 + g; n < NODES; n += BNBLK * 4) {
        float v = h1[(size_t)n * C1 + c];
        s += v;
        q = fmaf(v, v, q);
    }
    ls[t] = s; lq[t] = q;
    __syncthreads();
    if (t < 64) {
        bnpart[(size_t)blockIdx.x * 128 + t]      = ls[t] + ls[t + 64] + ls[t + 128] + ls[t + 192];
        bnpart[(size_t)blockIdx.x * 128 + 64 + t] = lq[t] + lq[t + 64] + lq[t + 128] + lq[t + 192];
    }
}

__global__ __launch_bounds__(64) void k_bnfinal(const float* __restrict__ bnpart,
                                                const float* __restrict__ gamma, const float* __restrict__ beta,
                                                float* bnscale, float* bnshift) {
    int c = threadIdx.x;
    if (c < C1) {
        float s = 0.f, q = 0.f;
        for (int b = 0; b < BNBLK; b++) {
            s += bnpart[(size_t)b * 128 + c];
            q += bnpart[(size_t)b * 128 + 64 + c];
        }
        float mu = s * (1.0f / NODES);
        float var = q * (1.0f / NODES) - mu * mu;
        if (var < 0.f) var = 0.f;
        float rinv = 1.0f / sqrtf(var + BNEPS);
        float sc = gamma[c] * rinv;
        bnscale[c] = sc;
        bnshift[c] = beta[c] - mu * sc;
    }
}

// ---------------- BN apply + ReLU + GEMM2 (+alpha dots) ----------------

__global__ __launch_bounds__(256) void k_bngemm2(const float* __restrict__ h1, const float* __restrict__ bnscale,
                                                 const float* __restrict__ bnshift, const float* __restrict__ W2s,
                                                 const float* __restrict__ wad2, const float* __restrict__ a2s,
                                                 float* __restrict__ hs2, float* __restrict__ as2,
                                                 float* __restrict__ ad2) {
    int n = blockIdx.x * 256 + threadIdx.x;
    if (n >= NODES) return;
    const float4* hr = reinterpret_cast<const float4*>(h1 + (size_t)n * C1);
    float h0 = 0.f, h1v = 0.f, adv = 0.f;
    #pragma unroll
    for (int c4 = 0; c4 < 16; c4++) {
        float4 v = hr[c4];
        float vv[4] = {v.x, v.y, v.z, v.w};
        #pragma unroll
        for (int j = 0; j < 4; j++) {
            int c = c4 * 4 + j;
            float y = fmaf(vv[j], bnscale[c], bnshift[c]);
            y = fmaxf(y, 0.f);
            h0 = fmaf(y, W2s[c * 2 + 0], h0);
            h1v = fmaf(y, W2s[c * 2 + 1], h1v);
            adv = fmaf(y, wad2[c], adv);
        }
    }
    hs2[n * 2 + 0] = h0;
    hs2[n * 2 + 1] = h1v;
    as2[n] = fmaf(h0, a2s[0], h1v * a2s[1]);
    ad2[n] = adv;
}

// ---------------- aggregation layer 2: wave per node, fully lane-parallel ----------------

__global__ __launch_bounds__(256) void k_agg2(const int* __restrict__ offs, const int* __restrict__ csr,
                                              const float* __restrict__ as2, const float* __restrict__ ad2,
                                              const float* __restrict__ hs2, const float* __restrict__ b2,
                                              float* __restrict__ out) {
    int w = threadIdx.x >> 6, lane = threadIdx.x & 63;
    int node = blockIdx.x * 4 + w;
    if (node >= NODES) return;
    int e0 = offs[node], e1 = offs[node + 1];
    float adn = ad2[node];
    float ssum = 0.f, A0 = 0.f, A1 = 0.f;
    const float2* h2 = reinterpret_cast<const float2*>(hs2);
    for (int base = e0; base < e1; base += 64) {
        int e = base + lane;
        bool valid = e < e1;
        int s = valid ? csr[e] : 0;
        float v = valid ? (as2[s] + adn) : -INFINITY;
        v = v > 0.f ? v : NEG * v;
        float p = __expf(fminf(v, 60.f));
        ssum += p;
        float2 hv = valid ? h2[s] : make_float2(0.f, 0.f);
        A0 = fmaf(p, hv.x, A0);
        A1 = fmaf(p, hv.y, A1);
    }
    #pragma unroll
    for (int o = 32; o; o >>= 1) {
        ssum += __shfl_xor(ssum, o);
        A0   += __shfl_xor(A0, o);
        A1   += __shfl_xor(A1, o);
    }
    if (lane == 0) {
        float inv = 1.0f / (ssum + 1e-16f);
        float2 r = make_float2(fmaf(A0, inv, b2[0]), fmaf(A1, inv, b2[1]));
        reinterpret_cast<float2*>(out)[node] = r;
    }
}

// ---------------- host ----------------

static inline size_t align256(size_t x) { return (x + 255) & ~size_t(255); }

extern "C" void kernel_launch(void* const* d_in, const int* in_sizes, int n_in,
                              void* d_out, int out_size, void* d_ws, size_t ws_size,
                              hipStream_t stream) {
    const float* x     = (const float*)d_in[0];
    const int*   ei    = (const int*)d_in[1];
    const float* W1s   = (const float*)d_in[2];
    const float* W1d   = (const float*)d_in[3];
    const float* a1s   = (const float*)d_in[4];
    const float* a1d   = (const float*)d_in[5];
    const float* b1    = (const float*)d_in[6];
    const float* gamma = (const float*)d_in[7];
    const float* beta  = (const float*)d_in[8];
    const float* W2s   = (const float*)d_in[9];
    const float* W2d   = (const float*)d_in[10];
    const float* a2s   = (const float*)d_in[11];
    const float* a2d   = (const float*)d_in[12];
    const float* b2    = (const float*)d_in[13];
    float* out = (float*)d_out;

    char* w = (char*)d_ws;
    size_t off = 0;
    auto alloc = [&](size_t bytes) -> void* {
        void* p = w + off;
        off = align256(off + bytes);
        return p;
    };
    int* offs     = (int*)alloc((size_t)(NODES + 1) * 4);
    int* bcur     = (int*)alloc(256 * 4);
    int* bbase    = (int*)alloc(256 * 4);
    int* csr      = (int*)alloc((size_t)ETOT * 4);
    __half* hs1h  = (__half*)alloc((size_t)NODES * C1 * 2);   // fp16 gather payload
    float* as1    = (float*)alloc((size_t)NODES * 4);
    float* ad1    = (float*)alloc((size_t)NODES * 4);
    float* h1     = (float*)alloc((size_t)NODES * C1 * 4);   // also aliases csr_tmp (see below)
    float* hs2    = (float*)alloc((size_t)NODES * 2 * 4);
    float* as2    = (float*)alloc((size_t)NODES * 4);
    float* ad2    = (float*)alloc((size_t)NODES * 4);
    float* wad1   = (float*)alloc(FIN * 4);
    float* wad2   = (float*)alloc(C1 * 4);
    float* bnpart = (float*)alloc((size_t)BNBLK * 128 * 4);
    float* bnsc   = (float*)alloc(64 * 4);
    float* bnsh   = (float*)alloc(64 * 4);
    if (off > ws_size) return;

    // csr_tmp (NBUCK*PCAP ints = 9.7MB) aliases h1 (25.6MB): k_build fully consumes
    // csr_tmp before k_agg1 produces h1 (in-order stream => safe).
    unsigned* csr_tmp = (unsigned*)h1;

    k_zero256<<<1, 256, 0, stream>>>(bcur);
    k_part<<<(NEDGE + PTILE - 1) / PTILE, 256, 0, stream>>>(ei, bcur, csr_tmp);
    k_bscan<<<1, 256, 0, stream>>>(bcur, bbase);
    k_build<<<NBUCK, 256, 0, stream>>>(csr_tmp, bcur, bbase, offs, csr);
    k_prep<<<1, 128, 0, stream>>>(W1d, a1d, W2d, a2d, wad1, wad2);
    k_gemm1<<<(NODES + 63) / 64, 256, 0, stream>>>(x, W1s, wad1, a1s, hs1h, as1, ad1);
    k_agg1<<<(NODES + 3) / 4, 256, 0, stream>>>(offs, csr, as1, ad1, hs1h, b1, h1);
    k_bnstats<<<BNBLK, 256, 0, stream>>>(h1, bnpart);
    k_bnfinal<<<1, 64, 0, stream>>>(bnpart, gamma, beta, bnsc, bnsh);
    k_bngemm2<<<(NODES + 255) / 256, 256, 0, stream>>>(h1, bnsc, bnsh, W2s, wad2, a2s, hs2, as2, ad2);
    k_agg2<<<(NODES + 3) / 4, 256, 0, stream>>>(offs, csr, as2, ad2, hs2, b2, out);
}

// Round 9
// 208.305 us; speedup vs baseline: 1.5081x; 1.0519x over previous
//
#include <hip/hip_runtime.h>
#include <hip/hip_fp16.h>
#include <math.h>

#define NODES 100000
#define NEDGE 1600000
#define ETOT  (NEDGE + NODES)
#define FIN   128
#define C1    64
#define NEG   0.2f
#define BNEPS 1e-5f
#define BNBLK 256

#define BK     512                         // nodes per bucket
#define NBUCK  ((NODES + BK - 1) / BK)     // 196
#define PCAP   12288                       // per-bucket edge capacity (mean 8673, +38 sigma)
#define PTILE  4096                        // edges per k_part block

// ---------------- bucketed CSR build ----------------

__global__ __launch_bounds__(256) void k_zero256(int* p) {
    p[threadIdx.x] = 0;
}

// P1: partition edges into buckets by dst>>9; pack src | (dst&511)<<17
__global__ __launch_bounds__(256) void k_part(const int* __restrict__ ei, int* bcur,
                                              unsigned* __restrict__ tmp) {
    __shared__ int hist[256], hbase[256], run[256];
    int t = threadIdx.x;
    hist[t] = 0; run[t] = 0;
    __syncthreads();
    const int* srcs = ei;
    const int* dsts = ei + NEDGE;
    int e_base = blockIdx.x * PTILE;
    unsigned pack[16];
    int bkt[16];
    #pragma unroll
    for (int i = 0; i < 16; i++) {
        int e = e_base + i * 256 + t;
        bool valid = e < NEDGE;
        int s = valid ? srcs[e] : 0;
        int d = valid ? dsts[e] : 0;
        if ((unsigned)d >= NODES || (unsigned)s >= NODES) valid = false;
        bkt[i] = valid ? (d >> 9) : -1;
        pack[i] = (unsigned)s | ((unsigned)(d & (BK - 1)) << 17);
        if (valid) atomicAdd(&hist[bkt[i]], 1);
    }
    __syncthreads();
    hbase[t] = hist[t] ? atomicAdd(&bcur[t], hist[t]) : 0;
    __syncthreads();
    #pragma unroll
    for (int i = 0; i < 16; i++) {
        if (bkt[i] >= 0) {
            int slot = atomicAdd(&run[bkt[i]], 1) + hbase[bkt[i]];
            if (slot < PCAP) tmp[(size_t)bkt[i] * PCAP + slot] = pack[i];
        }
    }
}

// exclusive scan of 256 bucket totals
__global__ __launch_bounds__(256) void k_bscan(const int* __restrict__ bcur, int* __restrict__ bbase) {
    __shared__ int lds[256];
    int t = threadIdx.x;
    int own = bcur[t];
    lds[t] = own;
    __syncthreads();
    for (int o = 1; o < 256; o <<= 1) {
        int add = (t >= o) ? lds[t - o] : 0;
        __syncthreads();
        lds[t] += add;
        __syncthreads();
    }
    bbase[t] = lds[t] - own;
}

// P2: per bucket: per-node counts -> local scan (offs) -> LDS scatter -> coalesced csr write
__global__ __launch_bounds__(256) void k_build(const unsigned* __restrict__ tmp, const int* __restrict__ bcur,
                                               const int* __restrict__ bbase, int* __restrict__ offs,
                                               int* __restrict__ csr) {
    __shared__ int cnt[BK];        // per-node edge count, then cursor
    __shared__ int ps[256];        // pair-sum scan
    __shared__ int stage[PCAP + BK];
    int t = threadIdx.x;
    int b = blockIdx.x;
    int ecnt = bcur[b]; if (ecnt > PCAP) ecnt = PCAP;
    int csrbase = bbase[b] + BK * b;   // all earlier buckets have BK valid nodes (self-loops)
    const unsigned* ebuf = tmp + (size_t)b * PCAP;

    cnt[t] = 0; cnt[t + 256] = 0;
    __syncthreads();
    for (int e = t; e < ecnt; e += 256) {
        int dl = (ebuf[e] >> 17) & (BK - 1);
        atomicAdd(&cnt[dl], 1);
    }
    __syncthreads();
    // local exclusive scan over 512 counts (+1 self-loop per valid node)
    int i0 = 2 * t, i1 = 2 * t + 1;
    int g0 = b * BK + i0, g1 = b * BK + i1;
    int c0 = cnt[i0] + (g0 < NODES ? 1 : 0);
    int c1 = cnt[i1] + (g1 < NODES ? 1 : 0);
    int own = c0 + c1;
    ps[t] = own;
    __syncthreads();
    for (int o = 1; o < 256; o <<= 1) {
        int add = (t >= o) ? ps[t - o] : 0;
        __syncthreads();
        ps[t] += add;
        __syncthreads();
    }
    int excl0 = ps[t] - own;
    int excl1 = excl0 + c0;
    int total = ps[255];
    __syncthreads();
    // cursors + self-loops + offs
    if (g0 < NODES) {
        stage[excl0] = g0;
        cnt[i0] = excl0 + 1;
        offs[g0] = csrbase + excl0;
    }
    if (g1 < NODES) {
        stage[excl1] = g1;
        cnt[i1] = excl1 + 1;
        offs[g1] = csrbase + excl1;
    }
    if (b == NBUCK - 1 && t == 0) offs[NODES] = ETOT;
    __syncthreads();
    for (int e = t; e < ecnt; e += 256) {
        unsigned p = ebuf[e];
        int dl = (p >> 17) & (BK - 1);
        int slot = atomicAdd(&cnt[dl], 1);
        stage[slot] = (int)(p & 0x1FFFFu);
    }
    __syncthreads();
    for (int j = t; j < total; j += 256) csr[csrbase + j] = stage[j];
}

// ---------------- small precomputed vectors ----------------

__global__ __launch_bounds__(128) void k_prep(const float* __restrict__ W1d, const float* __restrict__ a1d,
                                              const float* __restrict__ W2d, const float* __restrict__ a2d,
                                              float* wad1, float* wad2) {
    int t = threadIdx.x;
    if (t < FIN) {
        float acc = 0.f;
        for (int c = 0; c < C1; c++) acc = fmaf(W1d[t * C1 + c], a1d[c], acc);
        wad1[t] = acc;
    }
    if (t < C1) {
        wad2[t] = fmaf(W2d[t * 2], a2d[0], W2d[t * 2 + 1] * a2d[1]);
    }
}

// ---------------- GEMM1: hs1(fp16) = x@W1_src, ad1 = x@wad1, as1 = hs1@a1_src ----------------
// lane = node (64/block), wave = 16-channel group. x tile in LDS; W via wave-uniform
// scalar loads (scalar cache). hs1 stored as fp16 (halves agg1's gather bytes);
// as1 computed from fp32 accumulators in-register (no precision loss).

__global__ __launch_bounds__(256) void k_gemm1(const float* __restrict__ x, const float* __restrict__ Ws,
                                               const float* __restrict__ wad, const float* __restrict__ a_src,
                                               __half* __restrict__ hsh, float* __restrict__ as_out,
                                               float* __restrict__ ad_out) {
    __shared__ float4 xs[64 * 33];     // 33.8 KB
    __shared__ float  part[4][64];
    int t = threadIdx.x;
    int lane = t & 63;
    int cg = __builtin_amdgcn_readfirstlane(t >> 6);   // wave-uniform channel group
    int n0 = blockIdx.x * 64;

    // stage x tile, 64B-coalesced: thread quad (q=t&3) covers consecutive float4s
    {
        int node_l = t >> 2, q = t & 3;
        bool v = (n0 + node_l) < NODES;
        const float4* xr = reinterpret_cast<const float4*>(x + (size_t)(n0 + node_l) * FIN);
        #pragma unroll
        for (int i = 0; i < 8; i++) {
            int j = i * 4 + q;
            xs[node_l * 33 + j] = v ? xr[j] : make_float4(0.f, 0.f, 0.f, 0.f);
        }
    }
    __syncthreads();

    const float* __restrict__ Wcg = Ws + cg * 16;     // uniform base (SGPR)
    float acc[16];
    #pragma unroll
    for (int c = 0; c < 16; c++) acc[c] = 0.f;
    float adacc = 0.f;

    for (int k4 = 0; k4 < 32; k4++) {
        float4 xv = xs[lane * 33 + k4];
        float xk[4] = {xv.x, xv.y, xv.z, xv.w};
        #pragma unroll
        for (int kk = 0; kk < 4; kk++) {
            int k = k4 * 4 + kk;
            const float* __restrict__ wr = Wcg + (size_t)k * C1;   // uniform -> s_load
            #pragma unroll
            for (int c = 0; c < 16; c++) acc[c] = fmaf(xk[kk], wr[c], acc[c]);
            if (cg == 0) adacc = fmaf(xk[kk], wad[k], adacc);
        }
    }

    float asp = 0.f;
    #pragma unroll
    for (int c = 0; c < 16; c++) asp = fmaf(acc[c], a_src[cg * 16 + c], asp);
    part[cg][lane] = asp;
    int n = n0 + lane;
    if (n < NODES) {
        // pack 16 fp32 -> 16 fp16 -> two uint4 stores (32B)
        unsigned pk[8];
        #pragma unroll
        for (int j = 0; j < 8; j++) {
            __half2 h2 = __floats2half2_rn(acc[2 * j], acc[2 * j + 1]);
            pk[j] = *reinterpret_cast<unsigned*>(&h2);
        }
        uint4* dst = reinterpret_cast<uint4*>(hsh + (size_t)n * C1 + cg * 16);
        dst[0] = make_uint4(pk[0], pk[1], pk[2], pk[3]);
        dst[1] = make_uint4(pk[4], pk[5], pk[6], pk[7]);
    }
    __syncthreads();
    if (cg == 0 && n < NODES) {
        as_out[n] = part[0][lane] + part[1][lane] + part[2][lane] + part[3][lane];
        ad_out[n] = adacc;
    }
}

// ---------------- aggregation layer 1 ----------------
// wave per node. Softmax phase: 64 edges lane-parallel (alpha = exp(e)/sum,
// max dropped algebraically; clamp 60). Gather phase: 4 groups x 16 lanes;
// each group owns one edge per step, lane reads half4 (8B) -> one vmem
// instruction covers 4 rows (512B). 2x unroll for MLP. Invalid edges have
// p=0/s=0 so the ragged tail is self-handling. Group partials reduced via
// shfl_xor(16,32) at the end.

__global__ __launch_bounds__(256) void k_agg1(const int* __restrict__ offs, const int* __restrict__ csr,
                                              const float* __restrict__ as1, const float* __restrict__ ad1,
                                              const __half* __restrict__ hsh, const float* __restrict__ b1,
                                              float* __restrict__ h1) {
    int w = threadIdx.x >> 6, lane = threadIdx.x & 63;
    int node = blockIdx.x * 4 + w;
    if (node >= NODES) return;
    int e0 = offs[node], e1 = offs[node + 1];
    float adn = ad1[node];
    int g = lane >> 4;          // edge-group 0..3
    int l = lane & 15;          // channels 4l..4l+3
    float acc0 = 0.f, acc1 = 0.f, acc2 = 0.f, acc3 = 0.f;
    float ssum = 0.f;
    for (int base = e0; base < e1; base += 64) {
        int cnt = e1 - base; if (cnt > 64) cnt = 64;
        bool valid = lane < cnt;
        int s = valid ? csr[base + lane] : 0;
        float v;
        if (valid) {
            v = as1[s] + adn;
            v = v > 0.f ? v : NEG * v;
            v = __expf(fminf(v, 60.f));
        } else {
            v = 0.f;
        }
        float p = v;
        ssum += p;
        int steps = (cnt + 3) >> 2;
        int j = 0;
        for (; j + 2 <= steps; j += 2) {
            int   idx0 = j * 4 + g,        idx1 = idx0 + 4;
            int   sv0 = __shfl(s, idx0);   int   sv1 = __shfl(s, idx1);
            float pv0 = __shfl(p, idx0);   float pv1 = __shfl(p, idx1);
            uint2 rv0 = *reinterpret_cast<const uint2*>(hsh + (size_t)sv0 * C1 + l * 4);
            uint2 rv1 = *reinterpret_cast<const uint2*>(hsh + (size_t)sv1 * C1 + l * 4);
            float2 a01 = __half22float2(*reinterpret_cast<__half2*>(&rv0.x));
            float2 a23 = __half22float2(*reinterpret_cast<__half2*>(&rv0.y));
            float2 b01 = __half22float2(*reinterpret_cast<__half2*>(&rv1.x));
            float2 b23 = __half22float2(*reinterpret_cast<__half2*>(&rv1.y));
            acc0 = fmaf(pv0, a01.x, acc0); acc1 = fmaf(pv0, a01.y, acc1);
            acc2 = fmaf(pv0, a23.x, acc2); acc3 = fmaf(pv0, a23.y, acc3);
            acc0 = fmaf(pv1, b01.x, acc0); acc1 = fmaf(pv1, b01.y, acc1);
            acc2 = fmaf(pv1, b23.x, acc2); acc3 = fmaf(pv1, b23.y, acc3);
        }
        if (j < steps) {
            int   idx = j * 4 + g;
            int   sv = __shfl(s, idx);
            float pv = __shfl(p, idx);
            uint2 rv = *reinterpret_cast<const uint2*>(hsh + (size_t)sv * C1 + l * 4);
            float2 a01 = __half22float2(*reinterpret_cast<__half2*>(&rv.x));
            float2 a23 = __half22float2(*reinterpret_cast<__half2*>(&rv.y));
            acc0 = fmaf(pv, a01.x, acc0); acc1 = fmaf(pv, a01.y, acc1);
            acc2 = fmaf(pv, a23.x, acc2); acc3 = fmaf(pv, a23.y, acc3);
        }
    }
    #pragma unroll
    for (int o = 32; o; o >>= 1) ssum += __shfl_xor(ssum, o);
    acc0 += __shfl_xor(acc0, 16); acc0 += __shfl_xor(acc0, 32);
    acc1 += __shfl_xor(acc1, 16); acc1 += __shfl_xor(acc1, 32);
    acc2 += __shfl_xor(acc2, 16); acc2 += __shfl_xor(acc2, 32);
    acc3 += __shfl_xor(acc3, 16); acc3 += __shfl_xor(acc3, 32);
    if (g == 0) {
        float inv = 1.0f / (ssum + 1e-16f);
        float4 bv = reinterpret_cast<const float4*>(b1)[l];
        float4 r = make_float4(fmaf(acc0, inv, bv.x), fmaf(acc1, inv, bv.y),
                               fmaf(acc2, inv, bv.z), fmaf(acc3, inv, bv.w));
        reinterpret_cast<float4*>(h1 + (size_t)node * C1)[l] = r;
    }
}

// ---------------- BN stats: deterministic per-block partials ----------------

__global__ __launch_bounds__(256) void k_bnstats(const float* __restrict__ h1, float* __restrict__ bnpart) {
    __shared__ float ls[256], lq[256];
    int t = threadIdx.x;
    int c = t & 63, g = t >> 6;
    float s = 0.f, q = 0.f;
    for (int n = blockIdx.x * 4 + g; n < NODES; n += BNBLK * 4) {
        float v = h1[(size_t)n * C1 + c];
        s += v;
        q = fmaf(v, v, q);
    }
    ls[t] = s; lq[t] = q;
    __syncthreads();
    if (t < 64) {
        bnpart[(size_t)blockIdx.x * 128 + t]      = ls[t] + ls[t + 64] + ls[t + 128] + ls[t + 192];
        bnpart[(size_t)blockIdx.x * 128 + 64 + t] = lq[t] + lq[t + 64] + lq[t + 128] + lq[t + 192];
    }
}

__global__ __launch_bounds__(64) void k_bnfinal(const float* __restrict__ bnpart,
                                                const float* __restrict__ gamma, const float* __restrict__ beta,
                                                float* bnscale, float* bnshift) {
    int c = threadIdx.x;
    if (c < C1) {
        float s = 0.f, q = 0.f;
        for (int b = 0; b < BNBLK; b++) {
            s += bnpart[(size_t)b * 128 + c];
            q += bnpart[(size_t)b * 128 + 64 + c];
        }
        float mu = s * (1.0f / NODES);
        float var = q * (1.0f / NODES) - mu * mu;
        if (var < 0.f) var = 0.f;
        float rinv = 1.0f / sqrtf(var + BNEPS);
        float sc = gamma[c] * rinv;
        bnscale[c] = sc;
        bnshift[c] = beta[c] - mu * sc;
    }
}

// ---------------- BN apply + ReLU + GEMM2 (+alpha dots) ----------------

__global__ __launch_bounds__(256) void k_bngemm2(const float* __restrict__ h1, const float* __restrict__ bnscale,
                                                 const float* __restrict__ bnshift, const float* __restrict__ W2s,
                                                 const float* __restrict__ wad2, const float* __restrict__ a2s,
                                                 float* __restrict__ hs2, float* __restrict__ as2,
                                                 float* __restrict__ ad2) {
    int n = blockIdx.x * 256 + threadIdx.x;
    if (n >= NODES) return;
    const float4* hr = reinterpret_cast<const float4*>(h1 + (size_t)n * C1);
    float h0 = 0.f, h1v = 0.f, adv = 0.f;
    #pragma unroll
    for (int c4 = 0; c4 < 16; c4++) {
        float4 v = hr[c4];
        float vv[4] = {v.x, v.y, v.z, v.w};
        #pragma unroll
        for (int j = 0; j < 4; j++) {
            int c = c4 * 4 + j;
            float y = fmaf(vv[j], bnscale[c], bnshift[c]);
            y = fmaxf(y, 0.f);
            h0 = fmaf(y, W2s[c * 2 + 0], h0);
            h1v = fmaf(y, W2s[c * 2 + 1], h1v);
            adv = fmaf(y, wad2[c], adv);
        }
    }
    hs2[n * 2 + 0] = h0;
    hs2[n * 2 + 1] = h1v;
    as2[n] = fmaf(h0, a2s[0], h1v * a2s[1]);
    ad2[n] = adv;
}

// ---------------- aggregation layer 2: wave per node, fully lane-parallel ----------------

__global__ __launch_bounds__(256) void k_agg2(const int* __restrict__ offs, const int* __restrict__ csr,
                                              const float* __restrict__ as2, const float* __restrict__ ad2,
                                              const float* __restrict__ hs2, const float* __restrict__ b2,
                                              float* __restrict__ out) {
    int w = threadIdx.x >> 6, lane = threadIdx.x & 63;
    int node = blockIdx.x * 4 + w;
    if (node >= NODES) return;
    int e0 = offs[node], e1 = offs[node + 1];
    float adn = ad2[node];
    float ssum = 0.f, A0 = 0.f, A1 = 0.f;
    const float2* h2 = reinterpret_cast<const float2*>(hs2);
    for (int base = e0; base < e1; base += 64) {
        int e = base + lane;
        bool valid = e < e1;
        int s = valid ? csr[e] : 0;
        float v = valid ? (as2[s] + adn) : -INFINITY;
        v = v > 0.f ? v : NEG * v;
        float p = __expf(fminf(v, 60.f));
        ssum += p;
        float2 hv = valid ? h2[s] : make_float2(0.f, 0.f);
        A0 = fmaf(p, hv.x, A0);
        A1 = fmaf(p, hv.y, A1);
    }
    #pragma unroll
    for (int o = 32; o; o >>= 1) {
        ssum += __shfl_xor(ssum, o);
        A0   += __shfl_xor(A0, o);
        A1   += __shfl_xor(A1, o);
    }
    if (lane == 0) {
        float inv = 1.0f / (ssum + 1e-16f);
        float2 r = make_float2(fmaf(A0, inv, b2[0]), fmaf(A1, inv, b2[1]));
        reinterpret_cast<float2*>(out)[node] = r;
    }
}

// ---------------- host ----------------

static inline size_t align256(size_t x) { return (x + 255) & ~size_t(255); }

extern "C" void kernel_launch(void* const* d_in, const int* in_sizes, int n_in,
                              void* d_out, int out_size, void* d_ws, size_t ws_size,
                              hipStream_t stream) {
    const float* x     = (const float*)d_in[0];
    const int*   ei    = (const int*)d_in[1];
    const float* W1s   = (const float*)d_in[2];
    const float* W1d   = (const float*)d_in[3];
    const float* a1s   = (const float*)d_in[4];
    const float* a1d   = (const float*)d_in[5];
    const float* b1    = (const float*)d_in[6];
    const float* gamma = (const float*)d_in[7];
    const float* beta  = (const float*)d_in[8];
    const float* W2s   = (const float*)d_in[9];
    const float* W2d   = (const float*)d_in[10];
    const float* a2s   = (const float*)d_in[11];
    const float* a2d   = (const float*)d_in[12];
    const float* b2    = (const float*)d_in[13];
    float* out = (float*)d_out;

    char* w = (char*)d_ws;
    size_t off = 0;
    auto alloc = [&](size_t bytes) -> void* {
        void* p = w + off;
        off = align256(off + bytes);
        return p;
    };
    int* offs     = (int*)alloc((size_t)(NODES + 1) * 4);
    int* bcur     = (int*)alloc(256 * 4);
    int* bbase    = (int*)alloc(256 * 4);
    int* csr      = (int*)alloc((size_t)ETOT * 4);
    __half* hs1h  = (__half*)alloc((size_t)NODES * C1 * 2);   // fp16 gather payload
    float* as1    = (float*)alloc((size_t)NODES * 4);
    float* ad1    = (float*)alloc((size_t)NODES * 4);
    float* h1     = (float*)alloc((size_t)NODES * C1 * 4);   // also aliases csr_tmp (see below)
    float* hs2    = (float*)alloc((size_t)NODES * 2 * 4);
    float* as2    = (float*)alloc((size_t)NODES * 4);
    float* ad2    = (float*)alloc((size_t)NODES * 4);
    float* wad1   = (float*)alloc(FIN * 4);
    float* wad2   = (float*)alloc(C1 * 4);
    float* bnpart = (float*)alloc((size_t)BNBLK * 128 * 4);
    float* bnsc   = (float*)alloc(64 * 4);
    float* bnsh   = (float*)alloc(64 * 4);
    if (off > ws_size) return;

    // csr_tmp (NBUCK*PCAP ints = 9.7MB) aliases h1 (25.6MB): k_build fully consumes
    // csr_tmp before k_agg1 produces h1 (in-order stream => safe).
    unsigned* csr_tmp = (unsigned*)h1;

    k_zero256<<<1, 256, 0, stream>>>(bcur);
    k_part<<<(NEDGE + PTILE - 1) / PTILE, 256, 0, stream>>>(ei, bcur, csr_tmp);
    k_bscan<<<1, 256, 0, stream>>>(bcur, bbase);
    k_build<<<NBUCK, 256, 0, stream>>>(csr_tmp, bcur, bbase, offs, csr);
    k_prep<<<1, 128, 0, stream>>>(W1d, a1d, W2d, a2d, wad1, wad2);
    k_gemm1<<<(NODES + 63) / 64, 256, 0, stream>>>(x, W1s, wad1, a1s, hs1h, as1, ad1);
    k_agg1<<<(NODES + 3) / 4, 256, 0, stream>>>(offs, csr, as1, ad1, hs1h, b1, h1);
    k_bnstats<<<BNBLK, 256, 0, stream>>>(h1, bnpart);
    k_bnfinal<<<1, 64, 0, stream>>>(bnpart, gamma, beta, bnsc, bnsh);
    k_bngemm2<<<(NODES + 255) / 256, 256, 0, stream>>>(h1, bnsc, bnsh, W2s, wad2, a2s, hs2, as2, ad2);
    k_agg2<<<(NODES + 3) / 4, 256, 0, stream>>>(offs, csr, as2, ad2, hs2, b2, out);
}

// Round 10
// 185.742 us; speedup vs baseline: 1.6913x; 1.1215x over previous
//
#include <hip/hip_runtime.h>
#include <hip/hip_fp16.h>
#include <math.h>

#define NODES 100000
#define NEDGE 1600000
#define ETOT  (NEDGE + NODES)
#define FIN   128
#define C1    64
#define NEG   0.2f
#define BNEPS 1e-5f
#define BNBLK 256

#define BK     512                         // nodes per bucket
#define NBUCK  ((NODES + BK - 1) / BK)     // 196
#define PCAP   12288                       // per-bucket edge capacity
#define PTILE  4096                        // edges per k_part block

typedef __attribute__((ext_vector_type(8))) short bf16x8;
typedef __attribute__((ext_vector_type(4))) float f32x4;

static __device__ __forceinline__ short f2bf(float f) {
    unsigned u = __builtin_bit_cast(unsigned, f);
    unsigned r = (u + 0x7FFFu + ((u >> 16) & 1u)) >> 16;
    return (short)r;
}

// ---------------- bucketed CSR build ----------------

__global__ __launch_bounds__(256) void k_zero256(int* p) {
    p[threadIdx.x] = 0;
}

// P1: partition edges into buckets by dst>>9; pack src | (dst&511)<<17
__global__ __launch_bounds__(256) void k_part(const int* __restrict__ ei, int* bcur,
                                              unsigned* __restrict__ tmp) {
    __shared__ int hist[256], hbase[256], run[256];
    int t = threadIdx.x;
    hist[t] = 0; run[t] = 0;
    __syncthreads();
    const int* srcs = ei;
    const int* dsts = ei + NEDGE;
    int e_base = blockIdx.x * PTILE;
    unsigned pack[16];
    int bkt[16];
    #pragma unroll
    for (int i = 0; i < 16; i++) {
        int e = e_base + i * 256 + t;
        bool valid = e < NEDGE;
        int s = valid ? srcs[e] : 0;
        int d = valid ? dsts[e] : 0;
        if ((unsigned)d >= NODES || (unsigned)s >= NODES) valid = false;
        bkt[i] = valid ? (d >> 9) : -1;
        pack[i] = (unsigned)s | ((unsigned)(d & (BK - 1)) << 17);
        if (valid) atomicAdd(&hist[bkt[i]], 1);
    }
    __syncthreads();
    hbase[t] = hist[t] ? atomicAdd(&bcur[t], hist[t]) : 0;
    __syncthreads();
    #pragma unroll
    for (int i = 0; i < 16; i++) {
        if (bkt[i] >= 0) {
            int slot = atomicAdd(&run[bkt[i]], 1) + hbase[bkt[i]];
            if (slot < PCAP) tmp[(size_t)bkt[i] * PCAP + slot] = pack[i];
        }
    }
}

// exclusive scan of 256 bucket totals
__global__ __launch_bounds__(256) void k_bscan(const int* __restrict__ bcur, int* __restrict__ bbase) {
    __shared__ int lds[256];
    int t = threadIdx.x;
    int own = bcur[t];
    lds[t] = own;
    __syncthreads();
    for (int o = 1; o < 256; o <<= 1) {
        int add = (t >= o) ? lds[t - o] : 0;
        __syncthreads();
        lds[t] += add;
        __syncthreads();
    }
    bbase[t] = lds[t] - own;
}

// P2: per bucket: per-node counts -> local scan (offs) -> LDS scatter -> coalesced csr write
__global__ __launch_bounds__(256) void k_build(const unsigned* __restrict__ tmp, const int* __restrict__ bcur,
                                               const int* __restrict__ bbase, int* __restrict__ offs,
                                               int* __restrict__ csr) {
    __shared__ int cnt[BK];
    __shared__ int ps[256];
    __shared__ int stage[PCAP + BK];
    int t = threadIdx.x;
    int b = blockIdx.x;
    int ecnt = bcur[b]; if (ecnt > PCAP) ecnt = PCAP;
    int csrbase = bbase[b] + BK * b;
    const unsigned* ebuf = tmp + (size_t)b * PCAP;

    cnt[t] = 0; cnt[t + 256] = 0;
    __syncthreads();
    for (int e = t; e < ecnt; e += 256) {
        int dl = (ebuf[e] >> 17) & (BK - 1);
        atomicAdd(&cnt[dl], 1);
    }
    __syncthreads();
    int i0 = 2 * t, i1 = 2 * t + 1;
    int g0 = b * BK + i0, g1 = b * BK + i1;
    int c0 = cnt[i0] + (g0 < NODES ? 1 : 0);
    int c1 = cnt[i1] + (g1 < NODES ? 1 : 0);
    int own = c0 + c1;
    ps[t] = own;
    __syncthreads();
    for (int o = 1; o < 256; o <<= 1) {
        int add = (t >= o) ? ps[t - o] : 0;
        __syncthreads();
        ps[t] += add;
        __syncthreads();
    }
    int excl0 = ps[t] - own;
    int excl1 = excl0 + c0;
    int total = ps[255];
    __syncthreads();
    if (g0 < NODES) {
        stage[excl0] = g0;
        cnt[i0] = excl0 + 1;
        offs[g0] = csrbase + excl0;
    }
    if (g1 < NODES) {
        stage[excl1] = g1;
        cnt[i1] = excl1 + 1;
        offs[g1] = csrbase + excl1;
    }
    if (b == NBUCK - 1 && t == 0) offs[NODES] = ETOT;
    __syncthreads();
    for (int e = t; e < ecnt; e += 256) {
        unsigned p = ebuf[e];
        int dl = (p >> 17) & (BK - 1);
        int slot = atomicAdd(&cnt[dl], 1);
        stage[slot] = (int)(p & 0x1FFFFu);
    }
    __syncthreads();
    for (int j = t; j < total; j += 256) csr[csrbase + j] = stage[j];
}

// ---------------- prep: wad vectors + W1s bf16 B-fragments ----------------
// Wfrag layout (shorts): idx = ((ct*4+it)*64 + lane)*8 + j
//   k = it*32 + (lane>>4)*8 + j ; ch = ct*16 + (lane&15) ; val = bf16(W1s[k][ch])

__global__ __launch_bounds__(256) void k_prep(const float* __restrict__ W1s,
                                              const float* __restrict__ W1d, const float* __restrict__ a1d,
                                              const float* __restrict__ W2d, const float* __restrict__ a2d,
                                              float* wad1, float* wad2, unsigned short* __restrict__ wfrag) {
    int t = threadIdx.x;
    int b = blockIdx.x;
    if (b == 32) {
        if (t < FIN) {
            float acc = 0.f;
            for (int c = 0; c < C1; c++) acc = fmaf(W1d[t * C1 + c], a1d[c], acc);
            wad1[t] = acc;
        }
        if (t < C1) {
            wad2[t] = fmaf(W2d[t * 2], a2d[0], W2d[t * 2 + 1] * a2d[1]);
        }
    } else {
        int idx = b * 256 + t;          // 0..8191
        int j  = idx & 7;
        int ln = (idx >> 3) & 63;
        int it = (idx >> 9) & 3;
        int ct = idx >> 11;
        int k  = it * 32 + (ln >> 4) * 8 + j;
        int ch = ct * 16 + (ln & 15);
        wfrag[idx] = (unsigned short)f2bf(W1s[k * C1 + ch]);
    }
}

// ---------------- GEMM1 via MFMA: hs1(fp16) = x@W1_src, ad1 = x@wad1, as1 = hs1@a1_src ----
// wave = 16 nodes x 64 ch. A-frag: row = lane&15, k = 8*(lane>>4)+j (+32*it), built
// in-register from coalesced fp32 x loads. B-frag precomputed (k_prep). C/D layout
// (m89-verified): col = lane&15, row = (lane>>4)*4 + reg. No LDS, no barriers.

__global__ __launch_bounds__(256) void k_gemm1(const float* __restrict__ x,
                                               const unsigned short* __restrict__ wfrag,
                                               const float* __restrict__ wad, const float* __restrict__ a_src,
                                               __half* __restrict__ hsh, float* __restrict__ as_out,
                                               float* __restrict__ ad_out) {
    int t = threadIdx.x;
    int lane = t & 63;
    int wv = t >> 6;
    int n0 = blockIdx.x * 64 + wv * 16;
    int li = lane & 15, g = lane >> 4;

    int row = n0 + li;
    bool rv = row < NODES;
    const float* xr = x + (size_t)row * FIN + g * 8;

    f32x4 acc0 = {0.f,0.f,0.f,0.f}, acc1 = {0.f,0.f,0.f,0.f};
    f32x4 acc2 = {0.f,0.f,0.f,0.f}, acc3 = {0.f,0.f,0.f,0.f};
    bf16x8 af[4];
    float adp = 0.f;

    #pragma unroll
    for (int it = 0; it < 4; it++) {
        float xv[8];
        if (rv) {
            float4 lo = *reinterpret_cast<const float4*>(xr + it * 32);
            float4 hi = *reinterpret_cast<const float4*>(xr + it * 32 + 4);
            xv[0]=lo.x; xv[1]=lo.y; xv[2]=lo.z; xv[3]=lo.w;
            xv[4]=hi.x; xv[5]=hi.y; xv[6]=hi.z; xv[7]=hi.w;
        } else {
            #pragma unroll
            for (int j = 0; j < 8; j++) xv[j] = 0.f;
        }
        const float* wr = wad + g * 8 + it * 32;
        float4 wlo = *reinterpret_cast<const float4*>(wr);
        float4 whi = *reinterpret_cast<const float4*>(wr + 4);
        adp = fmaf(xv[0], wlo.x, adp); adp = fmaf(xv[1], wlo.y, adp);
        adp = fmaf(xv[2], wlo.z, adp); adp = fmaf(xv[3], wlo.w, adp);
        adp = fmaf(xv[4], whi.x, adp); adp = fmaf(xv[5], whi.y, adp);
        adp = fmaf(xv[6], whi.z, adp); adp = fmaf(xv[7], whi.w, adp);
        bf16x8 a;
        #pragma unroll
        for (int j = 0; j < 8; j++) a[j] = f2bf(xv[j]);
        af[it] = a;
    }

    const bf16x8* wfv = reinterpret_cast<const bf16x8*>(wfrag);
    #pragma unroll
    for (int it = 0; it < 4; it++) {
        acc0 = __builtin_amdgcn_mfma_f32_16x16x32_bf16(af[it], wfv[(0*4+it)*64 + lane], acc0, 0, 0, 0);
        acc1 = __builtin_amdgcn_mfma_f32_16x16x32_bf16(af[it], wfv[(1*4+it)*64 + lane], acc1, 0, 0, 0);
        acc2 = __builtin_amdgcn_mfma_f32_16x16x32_bf16(af[it], wfv[(2*4+it)*64 + lane], acc2, 0, 0, 0);
        acc3 = __builtin_amdgcn_mfma_f32_16x16x32_bf16(af[it], wfv[(3*4+it)*64 + lane], acc3, 0, 0, 0);
    }

    // ad1: reduce k-slices across the 4 g-lanes of each row
    adp += __shfl_xor(adp, 16);
    adp += __shfl_xor(adp, 32);
    if (lane < 16 && rv) ad_out[row] = adp;

    // as1 partials: node = n0 + 4g + r, ch = ct*16 + li
    float a0 = a_src[0 * 16 + li], a1 = a_src[1 * 16 + li];
    float a2 = a_src[2 * 16 + li], a3 = a_src[3 * 16 + li];
    float asp0 = acc0[0]*a0 + acc1[0]*a1 + acc2[0]*a2 + acc3[0]*a3;
    float asp1 = acc0[1]*a0 + acc1[1]*a1 + acc2[1]*a2 + acc3[1]*a3;
    float asp2 = acc0[2]*a0 + acc1[2]*a1 + acc2[2]*a2 + acc3[2]*a3;
    float asp3 = acc0[3]*a0 + acc1[3]*a1 + acc2[3]*a2 + acc3[3]*a3;
    #pragma unroll
    for (int o = 1; o <= 8; o <<= 1) {
        asp0 += __shfl_xor(asp0, o);
        asp1 += __shfl_xor(asp1, o);
        asp2 += __shfl_xor(asp2, o);
        asp3 += __shfl_xor(asp3, o);
    }
    if ((lane & 12) == 0) {
        int r = lane & 3;
        int n = n0 + 4 * g + r;
        if (n < NODES) {
            float av = (r == 0) ? asp0 : (r == 1) ? asp1 : (r == 2) ? asp2 : asp3;
            as_out[n] = av;
        }
    }

    // hs1 fp16 stores: per (ct, r): 16-lane groups write 32B contiguous per node
    #pragma unroll
    for (int r = 0; r < 4; r++) {
        int n = n0 + 4 * g + r;
        if (n < NODES) {
            __half* hb = hsh + (size_t)n * C1 + li;
            hb[ 0] = __float2half(acc0[r]);
            hb[16] = __float2half(acc1[r]);
            hb[32] = __float2half(acc2[r]);
            hb[48] = __float2half(acc3[r]);
        }
    }
}

// ---------------- aggregation layer 1 ----------------
// wave per node. Softmax phase lane-parallel; gather phase: 4 groups x 16 lanes,
// lane reads half4 (8B) -> one vmem instruction covers 4 rows. 2x unroll.

__global__ __launch_bounds__(256) void k_agg1(const int* __restrict__ offs, const int* __restrict__ csr,
                                              const float* __restrict__ as1, const float* __restrict__ ad1,
                                              const __half* __restrict__ hsh, const float* __restrict__ b1,
                                              float* __restrict__ h1) {
    int w = threadIdx.x >> 6, lane = threadIdx.x & 63;
    int node = blockIdx.x * 4 + w;
    if (node >= NODES) return;
    int e0 = offs[node], e1 = offs[node + 1];
    float adn = ad1[node];
    int g = lane >> 4;
    int l = lane & 15;
    float acc0 = 0.f, acc1 = 0.f, acc2 = 0.f, acc3 = 0.f;
    float ssum = 0.f;
    for (int base = e0; base < e1; base += 64) {
        int cnt = e1 - base; if (cnt > 64) cnt = 64;
        bool valid = lane < cnt;
        int s = valid ? csr[base + lane] : 0;
        float v;
        if (valid) {
            v = as1[s] + adn;
            v = v > 0.f ? v : NEG * v;
            v = __expf(fminf(v, 60.f));
        } else {
            v = 0.f;
        }
        float p = v;
        ssum += p;
        int steps = (cnt + 3) >> 2;
        int j = 0;
        for (; j + 2 <= steps; j += 2) {
            int   idx0 = j * 4 + g,        idx1 = idx0 + 4;
            int   sv0 = __shfl(s, idx0);   int   sv1 = __shfl(s, idx1);
            float pv0 = __shfl(p, idx0);   float pv1 = __shfl(p, idx1);
            uint2 rv0 = *reinterpret_cast<const uint2*>(hsh + (size_t)sv0 * C1 + l * 4);
            uint2 rv1 = *reinterpret_cast<const uint2*>(hsh + (size_t)sv1 * C1 + l * 4);
            float2 a01 = __half22float2(*reinterpret_cast<__half2*>(&rv0.x));
            float2 a23 = __half22float2(*reinterpret_cast<__half2*>(&rv0.y));
            float2 b01 = __half22float2(*reinterpret_cast<__half2*>(&rv1.x));
            float2 b23 = __half22float2(*reinterpret_cast<__half2*>(&rv1.y));
            acc0 = fmaf(pv0, a01.x, acc0); acc1 = fmaf(pv0, a01.y, acc1);
            acc2 = fmaf(pv0, a23.x, acc2); acc3 = fmaf(pv0, a23.y, acc3);
            acc0 = fmaf(pv1, b01.x, acc0); acc1 = fmaf(pv1, b01.y, acc1);
            acc2 = fmaf(pv1, b23.x, acc2); acc3 = fmaf(pv1, b23.y, acc3);
        }
        if (j < steps) {
            int   idx = j * 4 + g;
            int   sv = __shfl(s, idx);
            float pv = __shfl(p, idx);
            uint2 rv = *reinterpret_cast<const uint2*>(hsh + (size_t)sv * C1 + l * 4);
            float2 a01 = __half22float2(*reinterpret_cast<__half2*>(&rv.x));
            float2 a23 = __half22float2(*reinterpret_cast<__half2*>(&rv.y));
            acc0 = fmaf(pv, a01.x, acc0); acc1 = fmaf(pv, a01.y, acc1);
            acc2 = fmaf(pv, a23.x, acc2); acc3 = fmaf(pv, a23.y, acc3);
        }
    }
    #pragma unroll
    for (int o = 32; o; o >>= 1) ssum += __shfl_xor(ssum, o);
    acc0 += __shfl_xor(acc0, 16); acc0 += __shfl_xor(acc0, 32);
    acc1 += __shfl_xor(acc1, 16); acc1 += __shfl_xor(acc1, 32);
    acc2 += __shfl_xor(acc2, 16); acc2 += __shfl_xor(acc2, 32);
    acc3 += __shfl_xor(acc3, 16); acc3 += __shfl_xor(acc3, 32);
    if (g == 0) {
        float inv = 1.0f / (ssum + 1e-16f);
        float4 bv = reinterpret_cast<const float4*>(b1)[l];
        float4 r = make_float4(fmaf(acc0, inv, bv.x), fmaf(acc1, inv, bv.y),
                               fmaf(acc2, inv, bv.z), fmaf(acc3, inv, bv.w));
        reinterpret_cast<float4*>(h1 + (size_t)node * C1)[l] = r;
    }
}

// ---------------- BN stats: deterministic per-block partials ----------------

__global__ __launch_bounds__(256) void k_bnstats(const float* __restrict__ h1, float* __restrict__ bnpart) {
    __shared__ float ls[256], lq[256];
    int t = threadIdx.x;
    int c = t & 63, g = t >> 6;
    float s = 0.f, q = 0.f;
    for (int n = blockIdx.x * 4 + g; n < NODES; n += BNBLK * 4) {
        float v = h1[(size_t)n * C1 + c];
        s += v;
        q = fmaf(v, v, q);
    }
    ls[t] = s; lq[t] = q;
    __syncthreads();
    if (t < 64) {
        bnpart[(size_t)blockIdx.x * 128 + t]      = ls[t] + ls[t + 64] + ls[t + 128] + ls[t + 192];
        bnpart[(size_t)blockIdx.x * 128 + 64 + t] = lq[t] + lq[t + 64] + lq[t + 128] + lq[t + 192];
    }
}

__global__ __launch_bounds__(64) void k_bnfinal(const float* __restrict__ bnpart,
                                                const float* __restrict__ gamma, const float* __restrict__ beta,
                                                float* bnscale, float* bnshift) {
    int c = threadIdx.x;
    if (c < C1) {
        float s = 0.f, q = 0.f;
        for (int b = 0; b < BNBLK; b++) {
            s += bnpart[(size_t)b * 128 + c];
            q += bnpart[(size_t)b * 128 + 64 + c];
        }
        float mu = s * (1.0f / NODES);
        float var = q * (1.0f / NODES) - mu * mu;
        if (var < 0.f) var = 0.f;
        float rinv = 1.0f / sqrtf(var + BNEPS);
        float sc = gamma[c] * rinv;
        bnscale[c] = sc;
        bnshift[c] = beta[c] - mu * sc;
    }
}

// ---------------- BN apply + ReLU + GEMM2 (+alpha dots) ----------------

__global__ __launch_bounds__(256) void k_bngemm2(const float* __restrict__ h1, const float* __restrict__ bnscale,
                                                 const float* __restrict__ bnshift, const float* __restrict__ W2s,
                                                 const float* __restrict__ wad2, const float* __restrict__ a2s,
                                                 float* __restrict__ hs2, float* __restrict__ as2,
                                                 float* __restrict__ ad2) {
    int n = blockIdx.x * 256 + threadIdx.x;
    if (n >= NODES) return;
    const float4* hr = reinterpret_cast<const float4*>(h1 + (size_t)n * C1);
    float h0 = 0.f, h1v = 0.f, adv = 0.f;
    #pragma unroll
    for (int c4 = 0; c4 < 16; c4++) {
        float4 v = hr[c4];
        float vv[4] = {v.x, v.y, v.z, v.w};
        #pragma unroll
        for (int j = 0; j < 4; j++) {
            int c = c4 * 4 + j;
            float y = fmaf(vv[j], bnscale[c], bnshift[c]);
            y = fmaxf(y, 0.f);
            h0 = fmaf(y, W2s[c * 2 + 0], h0);
            h1v = fmaf(y, W2s[c * 2 + 1], h1v);
            adv = fmaf(y, wad2[c], adv);
        }
    }
    hs2[n * 2 + 0] = h0;
    hs2[n * 2 + 1] = h1v;
    as2[n] = fmaf(h0, a2s[0], h1v * a2s[1]);
    ad2[n] = adv;
}

// ---------------- aggregation layer 2: wave per node, fully lane-parallel ----------------

__global__ __launch_bounds__(256) void k_agg2(const int* __restrict__ offs, const int* __restrict__ csr,
                                              const float* __restrict__ as2, const float* __restrict__ ad2,
                                              const float* __restrict__ hs2, const float* __restrict__ b2,
                                              float* __restrict__ out) {
    int w = threadIdx.x >> 6, lane = threadIdx.x & 63;
    int node = blockIdx.x * 4 + w;
    if (node >= NODES) return;
    int e0 = offs[node], e1 = offs[node + 1];
    float adn = ad2[node];
    float ssum = 0.f, A0 = 0.f, A1 = 0.f;
    const float2* h2 = reinterpret_cast<const float2*>(hs2);
    for (int base = e0; base < e1; base += 64) {
        int e = base + lane;
        bool valid = e < e1;
        int s = valid ? csr[e] : 0;
        float v = valid ? (as2[s] + adn) : -INFINITY;
        v = v > 0.f ? v : NEG * v;
        float p = __expf(fminf(v, 60.f));
        ssum += p;
        float2 hv = valid ? h2[s] : make_float2(0.f, 0.f);
        A0 = fmaf(p, hv.x, A0);
        A1 = fmaf(p, hv.y, A1);
    }
    #pragma unroll
    for (int o = 32; o; o >>= 1) {
        ssum += __shfl_xor(ssum, o);
        A0   += __shfl_xor(A0, o);
        A1   += __shfl_xor(A1, o);
    }
    if (lane == 0) {
        float inv = 1.0f / (ssum + 1e-16f);
        float2 r = make_float2(fmaf(A0, inv, b2[0]), fmaf(A1, inv, b2[1]));
        reinterpret_cast<float2*>(out)[node] = r;
    }
}

// ---------------- host ----------------

static inline size_t align256(size_t x) { return (x + 255) & ~size_t(255); }

extern "C" void kernel_launch(void* const* d_in, const int* in_sizes, int n_in,
                              void* d_out, int out_size, void* d_ws, size_t ws_size,
                              hipStream_t stream) {
    const float* x     = (const float*)d_in[0];
    const int*   ei    = (const int*)d_in[1];
    const float* W1s   = (const float*)d_in[2];
    const float* W1d   = (const float*)d_in[3];
    const float* a1s   = (const float*)d_in[4];
    const float* a1d   = (const float*)d_in[5];
    const float* b1    = (const float*)d_in[6];
    const float* gamma = (const float*)d_in[7];
    const float* beta  = (const float*)d_in[8];
    const float* W2s   = (const float*)d_in[9];
    const float* W2d   = (const float*)d_in[10];
    const float* a2s   = (const float*)d_in[11];
    const float* a2d   = (const float*)d_in[12];
    const float* b2    = (const float*)d_in[13];
    float* out = (float*)d_out;

    char* w = (char*)d_ws;
    size_t off = 0;
    auto alloc = [&](size_t bytes) -> void* {
        void* p = w + off;
        off = align256(off + bytes);
        return p;
    };
    int* offs     = (int*)alloc((size_t)(NODES + 1) * 4);
    int* bcur     = (int*)alloc(256 * 4);
    int* bbase    = (int*)alloc(256 * 4);
    int* csr      = (int*)alloc((size_t)ETOT * 4);
    __half* hs1h  = (__half*)alloc((size_t)NODES * C1 * 2);   // fp16 gather payload
    float* as1    = (float*)alloc((size_t)NODES * 4);
    float* ad1    = (float*)alloc((size_t)NODES * 4);
    float* h1     = (float*)alloc((size_t)NODES * C1 * 4);   // also aliases csr_tmp (see below)
    float* hs2    = (float*)alloc((size_t)NODES * 2 * 4);
    float* as2    = (float*)alloc((size_t)NODES * 4);
    float* ad2    = (float*)alloc((size_t)NODES * 4);
    float* wad1   = (float*)alloc(FIN * 4);
    float* wad2   = (float*)alloc(C1 * 4);
    unsigned short* wfrag = (unsigned short*)alloc(8192 * 2); // W1s bf16 B-fragments
    float* bnpart = (float*)alloc((size_t)BNBLK * 128 * 4);
    float* bnsc   = (float*)alloc(64 * 4);
    float* bnsh   = (float*)alloc(64 * 4);
    if (off > ws_size) return;

    // csr_tmp (NBUCK*PCAP ints = 9.7MB) aliases h1 (25.6MB): k_build fully consumes
    // csr_tmp before k_agg1 produces h1 (in-order stream => safe).
    unsigned* csr_tmp = (unsigned*)h1;

    k_zero256<<<1, 256, 0, stream>>>(bcur);
    k_part<<<(NEDGE + PTILE - 1) / PTILE, 256, 0, stream>>>(ei, bcur, csr_tmp);
    k_bscan<<<1, 256, 0, stream>>>(bcur, bbase);
    k_build<<<NBUCK, 256, 0, stream>>>(csr_tmp, bcur, bbase, offs, csr);
    k_prep<<<33, 256, 0, stream>>>(W1s, W1d, a1d, W2d, a2d, wad1, wad2, wfrag);
    k_gemm1<<<(NODES + 63) / 64, 256, 0, stream>>>(x, wfrag, wad1, a1s, hs1h, as1, ad1);
    k_agg1<<<(NODES + 3) / 4, 256, 0, stream>>>(offs, csr, as1, ad1, hs1h, b1, h1);
    k_bnstats<<<BNBLK, 256, 0, stream>>>(h1, bnpart);
    k_bnfinal<<<1, 64, 0, stream>>>(bnpart, gamma, beta, bnsc, bnsh);
    k_bngemm2<<<(NODES + 255) / 256, 256, 0, stream>>>(h1, bnsc, bnsh, W2s, wad2, a2s, hs2, as2, ad2);
    k_agg2<<<(NODES + 3) / 4, 256, 0, stream>>>(offs, csr, as2, ad2, hs2, b2, out);
}